// Round 1
// baseline (2448.561 us; speedup 1.0000x reference)
//
#include <hip/hip_runtime.h>

// ---------------- problem constants ----------------
constexpr int ND_   = 12288;           // 3*B
constexpr int K_    = 10;
constexpr int NTOT  = ND_ * (1 + K_);  // 135168
constexpr int B_    = 4096;

// ws layout (float offsets)
constexpr size_t OFF_H    = 0;                       // NTOT*128 = 17,301,504
constexpr size_t OFF_EMB  = 17301504;                // ND_*128  = 1,572,864
constexpr size_t OFF_WIH  = 18874368;                // 128*384*4 = 196,608
constexpr size_t OFF_WHH  = 19070976;                // 32*384*4  = 49,152
constexpr size_t OFF_WK   = 19120128;                // 96*128*4  = 49,152
constexpr size_t OFF_WV   = 19169280;                // 49,152
constexpr size_t OFF_WQ   = 19218432;                // 32*128*4  = 16,384
constexpr size_t OFF_WO   = 19234816;                // 64*128*4  = 32,768
constexpr size_t OFF_SW   = 19267584;                // 16,384
constexpr size_t OFF_DW   = 19283968;                // 16,384
constexpr size_t OFF_QZ   = 19300352;                // 128

#define DEVFN __device__ __forceinline__

DEVFN float dot4(const float4 a, const float4 b, float acc) {
  acc = fmaf(a.x, b.x, acc);
  acc = fmaf(a.y, b.y, acc);
  acc = fmaf(a.z, b.z, acc);
  acc = fmaf(a.w, b.w, acc);
  return acc;
}

DEVFN float sigmoidf_(float x) { return 1.0f / (1.0f + expf(-x)); }

// ---------------- k0: weight panelization ----------------
// Panels: P[k4][j] = float4{ W[j][4k4 .. 4k4+3] }  (coalesced across j, 4 K-steps per load)
__global__ void k0_prep(const float* __restrict__ w_ih, const float* __restrict__ w_hh,
                        const float* __restrict__ wk,  const float* __restrict__ wv,
                        const float* __restrict__ wq,  const float* __restrict__ wo,
                        const float* __restrict__ sw,  const float* __restrict__ dwm,
                        float4* __restrict__ WihP, float4* __restrict__ WhhP,
                        float4* __restrict__ WkP,  float4* __restrict__ WvP,
                        float4* __restrict__ WqP,  float4* __restrict__ WoP,
                        float4* __restrict__ SwP,  float4* __restrict__ DwP)
{
  int id = blockIdx.x * 256 + threadIdx.x;
  if (id < 49152) {            // W_ih (384x512) -> [128][384]
    int k4 = id / 384, j = id % 384;
    const float* s = w_ih + j * 512 + 4 * k4;
    WihP[id] = make_float4(s[0], s[1], s[2], s[3]);
    return;
  }
  id -= 49152;
  if (id < 12288) {            // W_hh (384x128) -> [32][384]
    int k4 = id / 384, j = id % 384;
    const float* s = w_hh + j * 128 + 4 * k4;
    WhhP[id] = make_float4(s[0], s[1], s[2], s[3]);
    return;
  }
  id -= 12288;
  if (id < 12288) {            // wk (128x384) -> [96][128]
    int k4 = id / 128, c = id % 128;
    const float* s = wk + c * 384 + 4 * k4;
    WkP[id] = make_float4(s[0], s[1], s[2], s[3]);
    return;
  }
  id -= 12288;
  if (id < 12288) {            // wv (128x384) -> [96][128]
    int k4 = id / 128, c = id % 128;
    const float* s = wv + c * 384 + 4 * k4;
    WvP[id] = make_float4(s[0], s[1], s[2], s[3]);
    return;
  }
  id -= 12288;
  if (id < 4096) {             // wq (128x256), first 128 K only -> [32][128]
    int k4 = id / 128, c = id % 128;
    const float* s = wq + c * 256 + 4 * k4;
    WqP[id] = make_float4(s[0], s[1], s[2], s[3]);
    return;
  }
  id -= 4096;
  if (id < 8192) {             // wo (128x256) -> [64][128]
    int k4 = id / 128, c = id % 128;
    const float* s = wo + c * 256 + 4 * k4;
    WoP[id] = make_float4(s[0], s[1], s[2], s[3]);
    return;
  }
  id -= 8192;
  if (id < 4096) {             // ep_sw (128x128) -> [32][128]
    int k4 = id / 128, c = id % 128;
    const float* s = sw + c * 128 + 4 * k4;
    SwP[id] = make_float4(s[0], s[1], s[2], s[3]);
    return;
  }
  id -= 4096;
  if (id < 4096) {             // ep_dw (128x128) -> [32][128]
    int k4 = id / 128, c = id % 128;
    const float* s = dwm + c * 128 + 4 * k4;
    DwP[id] = make_float4(s[0], s[1], s[2], s[3]);
    return;
  }
}

// qzero[c] = bq[c] + sum_k cos(time_b[k]) * wq[c][128+k]  (same for every row)
__global__ void k0_qzero(const float* __restrict__ time_b, const float* __restrict__ wq,
                         const float* __restrict__ bq, float* __restrict__ qzero)
{
  int c = threadIdx.x;
  float acc = bq[c];
  for (int k = 0; k < 128; ++k)
    acc = fmaf(cosf(time_b[k]), wq[c * 256 + 128 + k], acc);
  qzero[c] = acc;
}

// ---------------- k1: time-encode + GRU -> h[N][128] ----------------
// 16 rows per block, 128 threads; thread jj owns output channel jj of all 3 gates.
__global__ __launch_bounds__(128) void k1_h(
    const int* __restrict__ nodes, const float* __restrict__ nfeat,
    const float* __restrict__ mem_data, const float* __restrict__ mem_time,
    const float* __restrict__ mail_data, const float* __restrict__ mail_time,
    const float* __restrict__ time_w, const float* __restrict__ time_b,
    const float* __restrict__ b_ih, const float* __restrict__ b_hh,
    const float4* __restrict__ WihP, const float4* __restrict__ WhhP,
    float* __restrict__ hbuf)
{
  __shared__ float mail[16][512];
  __shared__ float memv[16][128];
  __shared__ int nid[16];
  const int tid = threadIdx.x;
  const int i0 = blockIdx.x * 16;
  if (tid < 16) nid[tid] = nodes[i0 + tid];
  const float tw = time_w[tid], tb = time_b[tid];
  __syncthreads();
  for (int r = 0; r < 16; ++r) {
    const int n = nid[r];
    const float d = mail_time[n] - mem_time[n];
    const float* md = mail_data + (size_t)n * 384;
    mail[r][tid]       = md[tid];
    mail[r][128 + tid] = md[128 + tid];
    mail[r][256 + tid] = md[256 + tid];
    mail[r][384 + tid] = cosf(fmaf(d, tw, tb));
    memv[r][tid] = mem_data[(size_t)n * 128 + tid];
  }
  __syncthreads();

  float accR[16], accZ[16], gin[16], ghn[16];
  #pragma unroll
  for (int r = 0; r < 16; ++r) { accR[r] = 0.f; accZ[r] = 0.f; gin[r] = 0.f; ghn[r] = 0.f; }

  for (int k4 = 0; k4 < 128; ++k4) {      // gi = mail @ W_ih^T
    const float4 wr = WihP[k4 * 384 + tid];
    const float4 wz = WihP[k4 * 384 + 128 + tid];
    const float4 wn = WihP[k4 * 384 + 256 + tid];
    #pragma unroll
    for (int r = 0; r < 16; ++r) {
      const float4 m = ((const float4*)mail[r])[k4];
      accR[r] = dot4(m, wr, accR[r]);
      accZ[r] = dot4(m, wz, accZ[r]);
      gin[r]  = dot4(m, wn, gin[r]);
    }
  }
  for (int k4 = 0; k4 < 32; ++k4) {       // gh = mem @ W_hh^T
    const float4 wr = WhhP[k4 * 384 + tid];
    const float4 wz = WhhP[k4 * 384 + 128 + tid];
    const float4 wn = WhhP[k4 * 384 + 256 + tid];
    #pragma unroll
    for (int r = 0; r < 16; ++r) {
      const float4 m = ((const float4*)memv[r])[k4];
      accR[r] = dot4(m, wr, accR[r]);
      accZ[r] = dot4(m, wz, accZ[r]);
      ghn[r]  = dot4(m, wn, ghn[r]);
    }
  }

  const float bR  = b_ih[tid] + b_hh[tid];
  const float bZ  = b_ih[128 + tid] + b_hh[128 + tid];
  const float bNi = b_ih[256 + tid];
  const float bNh = b_hh[256 + tid];
  for (int r = 0; r < 16; ++r) {
    const int n = nid[r];
    const float gr  = sigmoidf_(accR[r] + bR);
    const float gz  = sigmoidf_(accZ[r] + bZ);
    const float gn  = tanhf(gin[r] + bNi + gr * (ghn[r] + bNh));
    const float mem = (1.0f - gz) * gn + gz * memv[r][tid];
    hbuf[(size_t)(i0 + r) * 128 + tid] = nfeat[(size_t)n * 128 + tid] + mem;
  }
}

// ---------------- k2: fused Q/K/V + attention + out-proj + LN -> emb[ND][128] ----------------
// 4 dst rows per block, 128 threads; head = c>>6 maps exactly to the wave.
__global__ __launch_bounds__(128) void k2_att(
    const float* __restrict__ hbuf, const int* __restrict__ eids,
    const float* __restrict__ dt_nbr, const float* __restrict__ efeat,
    const float* __restrict__ time_w, const float* __restrict__ time_b,
    const float* __restrict__ qzero, const float4* __restrict__ WqP,
    const float4* __restrict__ WkP, const float4* __restrict__ WvP,
    const float* __restrict__ bk, const float* __restrict__ bv,
    const float4* __restrict__ WoP, const float* __restrict__ bo,
    const float* __restrict__ ln_g, const float* __restrict__ ln_b,
    float* __restrict__ emb)
{
  __shared__ float dsth[4][128];
  __shared__ float kin[4][384];
  __shared__ float aggl[4][128];
  __shared__ float redS[2][4], redQ[2][4];
  const int c = threadIdx.x;
  const int wave = c >> 6;
  const int i0 = blockIdx.x * 4;
  const float tw = time_w[c], tb = time_b[c];

  for (int r = 0; r < 4; ++r) dsth[r][c] = hbuf[(size_t)(i0 + r) * 128 + c];
  __syncthreads();

  // Q (zero_tenc part precomputed in qzero)
  float qreg[4];
  {
    const float qz = qzero[c];
    #pragma unroll
    for (int r = 0; r < 4; ++r) qreg[r] = qz;
    for (int k4 = 0; k4 < 32; ++k4) {
      const float4 w = WqP[k4 * 128 + c];
      #pragma unroll
      for (int r = 0; r < 4; ++r)
        qreg[r] = dot4(((const float4*)dsth[r])[k4], w, qreg[r]);
    }
  }

  const float bkc = bk[c], bvc = bv[c];
  float m[4], l[4], ag[4];
  #pragma unroll
  for (int r = 0; r < 4; ++r) { m[r] = -1e30f; l[r] = 0.f; ag[r] = 0.f; }

  for (int kk = 0; kk < K_; ++kk) {
    __syncthreads();  // protect kin against previous iteration's readers
    for (int r = 0; r < 4; ++r) {
      const int i = i0 + r;
      const int   eid = eids[i * K_ + kk];
      const float dt  = dt_nbr[i * K_ + kk];
      kin[r][c]       = hbuf[(size_t)(ND_ + i * K_ + kk) * 128 + c];
      kin[r][128 + c] = efeat[(size_t)eid * 128 + c];
      kin[r][256 + c] = cosf(fmaf(dt, tw, tb));
    }
    __syncthreads();

    float kfa[4], vfa[4];
    #pragma unroll
    for (int r = 0; r < 4; ++r) { kfa[r] = bkc; vfa[r] = bvc; }
    for (int k4 = 0; k4 < 96; ++k4) {
      const float4 wk4 = WkP[k4 * 128 + c];
      const float4 wv4 = WvP[k4 * 128 + c];
      #pragma unroll
      for (int r = 0; r < 4; ++r) {
        const float4 ki = ((const float4*)kin[r])[k4];
        kfa[r] = dot4(ki, wk4, kfa[r]);
        vfa[r] = dot4(ki, wv4, vfa[r]);
      }
    }
    #pragma unroll
    for (int r = 0; r < 4; ++r) {
      float p = qreg[r] * kfa[r];
      for (int s = 32; s; s >>= 1) p += __shfl_xor(p, s);   // head-sum over the wave's 64 lanes
      const float mn = fmaxf(m[r], p);
      const float sc = expf(m[r] - mn);
      const float e  = expf(p - mn);
      l[r]  = l[r] * sc + e;
      ag[r] = ag[r] * sc + e * vfa[r];
      m[r]  = mn;
    }
  }
  for (int r = 0; r < 4; ++r) aggl[r][c] = ag[r] / l[r];
  __syncthreads();

  // out = concat([dst_h, agg]) @ wo^T + bo, relu, layernorm
  float oacc[4];
  {
    const float boc = bo[c];
    #pragma unroll
    for (int r = 0; r < 4; ++r) oacc[r] = boc;
    for (int k4 = 0; k4 < 32; ++k4) {
      const float4 w = WoP[k4 * 128 + c];
      #pragma unroll
      for (int r = 0; r < 4; ++r)
        oacc[r] = dot4(((const float4*)dsth[r])[k4], w, oacc[r]);
    }
    for (int k4 = 0; k4 < 32; ++k4) {
      const float4 w = WoP[(32 + k4) * 128 + c];
      #pragma unroll
      for (int r = 0; r < 4; ++r)
        oacc[r] = dot4(((const float4*)aggl[r])[k4], w, oacc[r]);
    }
  }
  #pragma unroll
  for (int r = 0; r < 4; ++r) {
    const float x = fmaxf(oacc[r], 0.f);
    float s = x, q2 = x * x;
    for (int t = 32; t; t >>= 1) { s += __shfl_xor(s, t); q2 += __shfl_xor(q2, t); }
    if ((c & 63) == 0) { redS[wave][r] = s; redQ[wave][r] = q2; }
  }
  __syncthreads();
  const float lng = ln_g[c], lnb = ln_b[c];
  for (int r = 0; r < 4; ++r) {
    const float sum = redS[0][r] + redS[1][r];
    const float sq  = redQ[0][r] + redQ[1][r];
    const float mu  = sum * (1.0f / 128.0f);
    const float var = sq * (1.0f / 128.0f) - mu * mu;
    const float x   = fmaxf(oacc[r], 0.f);
    emb[(size_t)(i0 + r) * 128 + c] = lng * (x - mu) * rsqrtf(var + 1e-5f) + lnb;
  }
}

// ---------------- k3: edge predictor -> out[B][2] ----------------
__global__ __launch_bounds__(128) void k3_ep(
    const float* __restrict__ emb, const float4* __restrict__ SwP,
    const float4* __restrict__ DwP, const float* __restrict__ ep_sb,
    const float* __restrict__ ep_db, const float* __restrict__ ep_ow,
    const float* __restrict__ ep_ob, float* __restrict__ out)
{
  __shared__ float se[128], de[128], ne[128];
  __shared__ float redp[2], redn[2];
  const int c = threadIdx.x;
  const int i = blockIdx.x;
  se[c] = emb[(size_t)i * 128 + c];
  de[c] = emb[(size_t)(B_ + i) * 128 + c];
  ne[c] = emb[(size_t)(2 * B_ + i) * 128 + c];
  __syncthreads();
  float sacc = ep_sb[c], dacc = ep_db[c], nacc = ep_db[c];
  for (int k4 = 0; k4 < 32; ++k4) {
    const float4 sw = SwP[k4 * 128 + c];
    const float4 dw = DwP[k4 * 128 + c];
    sacc = dot4(((const float4*)se)[k4], sw, sacc);
    dacc = dot4(((const float4*)de)[k4], dw, dacc);
    nacc = dot4(((const float4*)ne)[k4], dw, nacc);
  }
  const float ow = ep_ow[c];
  float pp = fmaxf(sacc + dacc, 0.f) * ow;
  float pn = fmaxf(sacc + nacc, 0.f) * ow;
  for (int t = 32; t; t >>= 1) { pp += __shfl_xor(pp, t); pn += __shfl_xor(pn, t); }
  if ((c & 63) == 0) { redp[c >> 6] = pp; redn[c >> 6] = pn; }
  __syncthreads();
  if (c == 0) {
    const float ob = ep_ob[0];
    out[i * 2]     = redp[0] + redp[1] + ob;
    out[i * 2 + 1] = redn[0] + redn[1] + ob;
  }
}

// ---------------- launch ----------------
extern "C" void kernel_launch(void* const* d_in, const int* in_sizes, int n_in,
                              void* d_out, int out_size, void* d_ws, size_t ws_size,
                              hipStream_t stream) {
  const int*   nodes     = (const int*)d_in[0];
  const int*   eids      = (const int*)d_in[1];
  const float* dt_nbr    = (const float*)d_in[2];
  const float* nfeat     = (const float*)d_in[3];
  const float* mem_data  = (const float*)d_in[4];
  const float* mem_time  = (const float*)d_in[5];
  const float* mail_data = (const float*)d_in[6];
  const float* mail_time = (const float*)d_in[7];
  const float* efeat     = (const float*)d_in[8];
  const float* time_w    = (const float*)d_in[9];
  const float* time_b    = (const float*)d_in[10];
  const float* gru_w_ih  = (const float*)d_in[11];
  const float* gru_w_hh  = (const float*)d_in[12];
  const float* gru_b_ih  = (const float*)d_in[13];
  const float* gru_b_hh  = (const float*)d_in[14];
  const float* wq        = (const float*)d_in[15];
  const float* bq        = (const float*)d_in[16];
  const float* wk        = (const float*)d_in[17];
  const float* bk        = (const float*)d_in[18];
  const float* wv        = (const float*)d_in[19];
  const float* bv        = (const float*)d_in[20];
  const float* wo        = (const float*)d_in[21];
  const float* bo        = (const float*)d_in[22];
  const float* ln_g      = (const float*)d_in[23];
  const float* ln_b      = (const float*)d_in[24];
  const float* ep_sw     = (const float*)d_in[25];
  const float* ep_sb     = (const float*)d_in[26];
  const float* ep_dw     = (const float*)d_in[27];
  const float* ep_db     = (const float*)d_in[28];
  const float* ep_ow     = (const float*)d_in[29];
  const float* ep_ob     = (const float*)d_in[30];
  float* out = (float*)d_out;
  float* ws  = (float*)d_ws;

  float* hbuf  = ws + OFF_H;
  float* emb   = ws + OFF_EMB;
  float4* WihP = (float4*)(ws + OFF_WIH);
  float4* WhhP = (float4*)(ws + OFF_WHH);
  float4* WkP  = (float4*)(ws + OFF_WK);
  float4* WvP  = (float4*)(ws + OFF_WV);
  float4* WqP  = (float4*)(ws + OFF_WQ);
  float4* WoP  = (float4*)(ws + OFF_WO);
  float4* SwP  = (float4*)(ws + OFF_SW);
  float4* DwP  = (float4*)(ws + OFF_DW);
  float* qzero = ws + OFF_QZ;

  k0_prep<<<416, 256, 0, stream>>>(gru_w_ih, gru_w_hh, wk, wv, wq, wo, ep_sw, ep_dw,
                                   WihP, WhhP, WkP, WvP, WqP, WoP, SwP, DwP);
  k0_qzero<<<1, 128, 0, stream>>>(time_b, wq, bq, qzero);
  k1_h<<<NTOT / 16, 128, 0, stream>>>(nodes, nfeat, mem_data, mem_time, mail_data,
                                      mail_time, time_w, time_b, gru_b_ih, gru_b_hh,
                                      WihP, WhhP, hbuf);
  k2_att<<<ND_ / 4, 128, 0, stream>>>(hbuf, eids, dt_nbr, efeat, time_w, time_b,
                                      qzero, WqP, WkP, WvP, bk, bv, WoP, bo,
                                      ln_g, ln_b, emb);
  k3_ep<<<B_, 128, 0, stream>>>(emb, SwP, DwP, ep_sb, ep_db, ep_ow, ep_ob, out);
}

// Round 2
// 1218.556 us; speedup vs baseline: 2.0094x; 2.0094x over previous
//
#include <hip/hip_runtime.h>

// ---------------- problem constants ----------------
constexpr int ND_   = 12288;           // 3*B
constexpr int K_    = 10;
constexpr int NTOT  = ND_ * (1 + K_);  // 135168
constexpr int B_    = 4096;
constexpr int RKV   = ND_ * K_;        // 122880

// ---------------- ws layout (float offsets) ----------------
constexpr size_t OFF_HB   = 0;          // ushort[NTOT*128]   (8,650,752 floats)
constexpr size_t OFF_KV   = 8650752;    // ushort[RKV*256]    (15,728,640 floats)
constexpr size_t OFF_EMB  = 24379392;   // float[ND_*128]     (1,572,864)
constexpr size_t OFF_WCAT = 25952256;   // ushort[640*512]    (163,840 floats)
constexpr size_t OFF_WKV  = 26116096;   // ushort[384*256]    (49,152 floats)
constexpr size_t OFF_BCAT = 26165248;   // float[512]
constexpr size_t OFF_BKV  = 26165760;   // float[256]
constexpr size_t OFF_WQP  = 26166016;   // float4[32*128]
constexpr size_t OFF_WOP  = 26182400;   // float4[64*128]
constexpr size_t OFF_SWP  = 26215168;   // float4[32*128]
constexpr size_t OFF_DWP  = 26231552;   // float4[32*128]
constexpr size_t OFF_QZ   = 26247936;   // float[128]

#define DEVFN __device__ __forceinline__

typedef __attribute__((ext_vector_type(8))) short bf16x8;
typedef __attribute__((ext_vector_type(4))) float f32x4;
#define MFMA16(a, b, c) __builtin_amdgcn_mfma_f32_16x16x32_bf16((a), (b), (c), 0, 0, 0)

DEVFN unsigned short f2bf(float x) {           // RNE float->bf16
  unsigned int u = __float_as_uint(x);
  u = (u + 0x7FFFu + ((u >> 16) & 1u)) >> 16;
  return (unsigned short)u;
}
DEVFN float bf2f(unsigned short h) { return __uint_as_float(((unsigned int)h) << 16); }

DEVFN float dot4(const float4 a, const float4 b, float acc) {
  acc = fmaf(a.x, b.x, acc);
  acc = fmaf(a.y, b.y, acc);
  acc = fmaf(a.z, b.z, acc);
  acc = fmaf(a.w, b.w, acc);
  return acc;
}
DEVFN float sigmoidf_(float x) { return 1.0f / (1.0f + expf(-x)); }

// ---------------- k0a: pack Wcat (GRU combined weight) as bf16 MFMA fragments ----------------
// Wcat[k=0..639][c'=0..511]; c' = (j>>5)*128 + g*32 + (j&31), g in {R,Z,Ni,Nh}, j = channel.
// k<512: mail part (w_ih, gates R/Z/Ni; zero for Nh); k>=512: mem part (w_hh, gates R/Z/Nh; zero for Ni).
// Fragment-major: frag f = kt*32 + nt (kt 0..19, nt 0..31); lane l elem j8 -> k = kt*32+(l>>4)*8+j8, c' = nt*16+(l&15).
__global__ void k0_packWcat(const float* __restrict__ w_ih, const float* __restrict__ w_hh,
                            unsigned short* __restrict__ WcatP)
{
  int gid = blockIdx.x * 256 + threadIdx.x;     // 327,680 total
  int f = gid >> 9, idx = gid & 511;
  int l = idx >> 3, j8 = idx & 7;
  int kt = f >> 5, nt = f & 31;
  int k = kt * 32 + (l >> 4) * 8 + j8;
  int c = nt * 16 + (l & 15);
  int q = c >> 7, g = (c >> 5) & 3, j = q * 32 + (c & 31);
  float w;
  if (g == 0)      w = (k < 512) ? w_ih[(size_t)j * 512 + k]         : w_hh[(size_t)j * 128 + (k - 512)];
  else if (g == 1) w = (k < 512) ? w_ih[(size_t)(128 + j) * 512 + k] : w_hh[(size_t)(128 + j) * 128 + (k - 512)];
  else if (g == 2) w = (k < 512) ? w_ih[(size_t)(256 + j) * 512 + k] : 0.0f;
  else             w = (k < 512) ? 0.0f : w_hh[(size_t)(256 + j) * 128 + (k - 512)];
  WcatP[gid] = f2bf(w);
}

// ---------------- k0b: pack Wkv (K|V projection) as bf16 fragments ----------------
// Wkv[k=0..383][c=0..255]; c<128 -> wk row c, else wv row c-128. frag f = kt*16 + nt.
__global__ void k0_packWkv(const float* __restrict__ wk, const float* __restrict__ wv,
                           unsigned short* __restrict__ WkvP)
{
  int gid = blockIdx.x * 256 + threadIdx.x;     // 98,304 total
  int f = gid >> 9, idx = gid & 511;
  int l = idx >> 3, j8 = idx & 7;
  int kt = f >> 4, nt = f & 15;
  int k = kt * 32 + (l >> 4) * 8 + j8;
  int c = nt * 16 + (l & 15);
  float w = (c < 128) ? wk[(size_t)c * 384 + k] : wv[(size_t)(c - 128) * 384 + k];
  WkvP[gid] = f2bf(w);
}

// ---------------- k0c: misc packs (fp32 panels for k2b/k3 + bias vectors) ----------------
__global__ void k0_misc(const float* __restrict__ wq, const float* __restrict__ wo,
                        const float* __restrict__ sw, const float* __restrict__ dwm,
                        const float* __restrict__ b_ih, const float* __restrict__ b_hh,
                        const float* __restrict__ bk, const float* __restrict__ bv,
                        float4* __restrict__ WqP, float4* __restrict__ WoP,
                        float4* __restrict__ SwP, float4* __restrict__ DwP,
                        float* __restrict__ bcat, float* __restrict__ bkv)
{
  int id = blockIdx.x * 256 + threadIdx.x;      // 21,248 total
  if (id < 4096) {            // wq (128x256), first 128 K -> [32][128]
    int k4 = id / 128, c = id % 128;
    const float* s = wq + c * 256 + 4 * k4;
    WqP[id] = make_float4(s[0], s[1], s[2], s[3]);
    return;
  }
  id -= 4096;
  if (id < 8192) {            // wo (128x256) -> [64][128]
    int k4 = id / 128, c = id % 128;
    const float* s = wo + c * 256 + 4 * k4;
    WoP[id] = make_float4(s[0], s[1], s[2], s[3]);
    return;
  }
  id -= 8192;
  if (id < 4096) {            // ep_sw (128x128) -> [32][128]
    int k4 = id / 128, c = id % 128;
    const float* s = sw + c * 128 + 4 * k4;
    SwP[id] = make_float4(s[0], s[1], s[2], s[3]);
    return;
  }
  id -= 4096;
  if (id < 4096) {            // ep_dw
    int k4 = id / 128, c = id % 128;
    const float* s = dwm + c * 128 + 4 * k4;
    DwP[id] = make_float4(s[0], s[1], s[2], s[3]);
    return;
  }
  id -= 4096;
  if (id < 512) {             // combined GRU bias, indexed by c'
    int q = id >> 7, g = (id >> 5) & 3, j = q * 32 + (id & 31);
    float b;
    if (g == 0)      b = b_ih[j] + b_hh[j];
    else if (g == 1) b = b_ih[128 + j] + b_hh[128 + j];
    else if (g == 2) b = b_ih[256 + j];
    else             b = b_hh[256 + j];
    bcat[id] = b;
    return;
  }
  id -= 512;
  if (id < 256) bkv[id] = (id < 128) ? bk[id] : bv[id - 128];
}

// qzero[c] = bq[c] + sum_k cos(time_b[k]) * wq[c][128+k]
__global__ void k0_qzero(const float* __restrict__ time_b, const float* __restrict__ wq,
                         const float* __restrict__ bq, float* __restrict__ qzero)
{
  int c = threadIdx.x;
  float acc = bq[c];
  for (int k = 0; k < 128; ++k)
    acc = fmaf(cosf(time_b[k]), wq[c * 256 + 128 + k], acc);
  qzero[c] = acc;
}

// ---------------- k1: gather + time-encode + MFMA GRU -> hbuf (bf16) ----------------
// 32 rows/block, 256 threads (4 waves). Wave w owns cols c' in [w*128,(w+1)*128) = channels
// j in [32w,32w+32) x all 4 gates -> epilogue register-local.
__global__ __launch_bounds__(256) void k1_gru(
    const int* __restrict__ nodes, const float* __restrict__ nfeat,
    const float* __restrict__ mem_data, const float* __restrict__ mem_time,
    const float* __restrict__ mail_data, const float* __restrict__ mail_time,
    const float* __restrict__ time_w, const float* __restrict__ time_b,
    const unsigned short* __restrict__ WcatP, const float* __restrict__ bcat,
    unsigned short* __restrict__ hb)
{
  __shared__ __align__(16) unsigned short Ash[32][648];   // 640 K + 8 pad (2-way bank alias = free)
  __shared__ int nid[32];
  __shared__ float drow[32];
  const int tid = threadIdx.x;
  const int i0 = blockIdx.x * 32;
  if (tid < 32) {
    int n = nodes[i0 + tid];
    nid[tid] = n;
    drow[tid] = mail_time[n] - mem_time[n];
  }
  float twv = 0.f, tbv = 0.f;
  if (tid >= 128) { twv = time_w[tid - 128]; tbv = time_b[tid - 128]; }
  __syncthreads();

  // stage A = [mail(384) | tenc(128) | mem(128)] as bf16, coalesced per row
  for (int r = 0; r < 32; ++r) {
    const int n = nid[r];
    if (tid < 96) {
      float4 v = ((const float4*)(mail_data + (size_t)n * 384))[tid];
      unsigned short* d = &Ash[r][tid * 4];
      d[0] = f2bf(v.x); d[1] = f2bf(v.y); d[2] = f2bf(v.z); d[3] = f2bf(v.w);
    } else if (tid < 128) {
      float4 v = ((const float4*)(mem_data + (size_t)n * 128))[tid - 96];
      unsigned short* d = &Ash[r][512 + (tid - 96) * 4];
      d[0] = f2bf(v.x); d[1] = f2bf(v.y); d[2] = f2bf(v.z); d[3] = f2bf(v.w);
    } else {
      Ash[r][384 + (tid - 128)] = f2bf(cosf(fmaf(drow[r], twv, tbv)));
    }
  }
  __syncthreads();

  const int w = tid >> 6, l = tid & 63;
  const int lc = l & 15, lr = l >> 4;

  f32x4 acc[2][8];
  #pragma unroll
  for (int m = 0; m < 2; ++m)
    #pragma unroll
    for (int bn = 0; bn < 8; ++bn) acc[m][bn] = (f32x4){0.f, 0.f, 0.f, 0.f};

  for (int kt = 0; kt < 20; ++kt) {
    bf16x8 a0 = *(const bf16x8*)&Ash[lc][kt * 32 + lr * 8];
    bf16x8 a1 = *(const bf16x8*)&Ash[16 + lc][kt * 32 + lr * 8];
    #pragma unroll
    for (int bn = 0; bn < 8; ++bn) {
      const bf16x8 bf = *(const bf16x8*)(WcatP + ((size_t)(kt * 32 + w * 8 + bn) * 64 + l) * 8);
      acc[0][bn] = MFMA16(a0, bf, acc[0][bn]);
      acc[1][bn] = MFMA16(a1, bf, acc[1][bn]);
    }
  }

  // GRU epilogue (register-local): ntile bn = g*2 + b
  float bg[4][2];
  #pragma unroll
  for (int g = 0; g < 4; ++g)
    #pragma unroll
    for (int b = 0; b < 2; ++b) bg[g][b] = bcat[w * 128 + (g * 2 + b) * 16 + lc];

  #pragma unroll
  for (int m = 0; m < 2; ++m) {
    #pragma unroll
    for (int rr = 0; rr < 4; ++rr) {
      const int rl = m * 16 + lr * 4 + rr;
      const int n = nid[rl];
      const size_t gi = (size_t)(i0 + rl);
      #pragma unroll
      for (int b = 0; b < 2; ++b) {
        const int j = w * 32 + b * 16 + lc;
        const float aR  = acc[m][0 + b][rr] + bg[0][b];
        const float aZ  = acc[m][2 + b][rr] + bg[1][b];
        const float aNi = acc[m][4 + b][rr] + bg[2][b];
        const float aNh = acc[m][6 + b][rr] + bg[3][b];
        const float r_  = sigmoidf_(aR);
        const float z_  = sigmoidf_(aZ);
        const float n_  = tanhf(aNi + r_ * aNh);
        const float mem = bf2f(Ash[rl][512 + j]);
        const float h   = nfeat[(size_t)n * 128 + j] + (1.0f - z_) * n_ + z_ * mem;
        hb[gi * 128 + j] = f2bf(h);
      }
    }
  }
}

// ---------------- k2a: gather + MFMA K/V projection -> KVb (bf16, [row][Kf128|Vf128]) ----------------
__global__ __launch_bounds__(256) void k2a_kv(
    const unsigned short* __restrict__ hb, const int* __restrict__ eids,
    const float* __restrict__ dt_nbr, const float* __restrict__ efeat,
    const float* __restrict__ time_w, const float* __restrict__ time_b,
    const unsigned short* __restrict__ WkvP, const float* __restrict__ bkv,
    unsigned short* __restrict__ KVb)
{
  __shared__ __align__(16) unsigned short Ash[32][392];   // 384 K + 8 pad
  __shared__ int eidv[32];
  __shared__ float dtv[32];
  const int tid = threadIdx.x;
  const int i0 = blockIdx.x * 32;
  if (tid < 32) { eidv[tid] = eids[i0 + tid]; dtv[tid] = dt_nbr[i0 + tid]; }
  float twv = 0.f, tbv = 0.f;
  if (tid >= 64 && tid < 192) { twv = time_w[tid - 64]; tbv = time_b[tid - 64]; }
  __syncthreads();

  for (int r = 0; r < 32; ++r) {
    if (tid < 32) {           // src_h row already bf16: direct 8B copies
      ((uint2*)&Ash[r][0])[tid] = ((const uint2*)(hb + (size_t)(ND_ + i0 + r) * 128))[tid];
    } else if (tid < 64) {
      int t = tid - 32;
      float4 v = ((const float4*)(efeat + (size_t)eidv[r] * 128))[t];
      unsigned short* d = &Ash[r][128 + t * 4];
      d[0] = f2bf(v.x); d[1] = f2bf(v.y); d[2] = f2bf(v.z); d[3] = f2bf(v.w);
    } else if (tid < 192) {
      Ash[r][256 + (tid - 64)] = f2bf(cosf(fmaf(dtv[r], twv, tbv)));
    }
  }
  __syncthreads();

  const int w = tid >> 6, l = tid & 63;
  const int lc = l & 15, lr = l >> 4;

  f32x4 acc[2][4];
  #pragma unroll
  for (int m = 0; m < 2; ++m)
    #pragma unroll
    for (int bn = 0; bn < 4; ++bn) acc[m][bn] = (f32x4){0.f, 0.f, 0.f, 0.f};

  for (int kt = 0; kt < 12; ++kt) {
    bf16x8 a0 = *(const bf16x8*)&Ash[lc][kt * 32 + lr * 8];
    bf16x8 a1 = *(const bf16x8*)&Ash[16 + lc][kt * 32 + lr * 8];
    #pragma unroll
    for (int bn = 0; bn < 4; ++bn) {
      const bf16x8 bf = *(const bf16x8*)(WkvP + ((size_t)(kt * 16 + w * 4 + bn) * 64 + l) * 8);
      acc[0][bn] = MFMA16(a0, bf, acc[0][bn]);
      acc[1][bn] = MFMA16(a1, bf, acc[1][bn]);
    }
  }

  float bb[4];
  #pragma unroll
  for (int bn = 0; bn < 4; ++bn) bb[bn] = bkv[w * 64 + bn * 16 + lc];

  #pragma unroll
  for (int m = 0; m < 2; ++m)
    #pragma unroll
    for (int rr = 0; rr < 4; ++rr) {
      const int rl = m * 16 + lr * 4 + rr;
      const size_t gr = (size_t)(i0 + rl);
      #pragma unroll
      for (int bn = 0; bn < 4; ++bn)
        KVb[gr * 256 + w * 64 + bn * 16 + lc] = f2bf(acc[m][bn][rr] + bb[bn]);
    }
}

// ---------------- k2b: Q + attention + out-proj + LN -> emb (fp32) ----------------
__global__ __launch_bounds__(128) void k2b_att(
    const unsigned short* __restrict__ hb, const unsigned short* __restrict__ KVb,
    const float* __restrict__ qzero, const float4* __restrict__ WqP,
    const float4* __restrict__ WoP, const float* __restrict__ bo,
    const float* __restrict__ ln_g, const float* __restrict__ ln_b,
    float* __restrict__ emb)
{
  __shared__ float dsth[4][128];
  __shared__ float aggl[4][128];
  __shared__ float redS[2][4], redQ[2][4];
  const int c = threadIdx.x;
  const int wave = c >> 6;
  const int i0 = blockIdx.x * 4;

  for (int r = 0; r < 4; ++r) dsth[r][c] = bf2f(hb[(size_t)(i0 + r) * 128 + c]);
  __syncthreads();

  float qreg[4];
  {
    const float qz = qzero[c];
    #pragma unroll
    for (int r = 0; r < 4; ++r) qreg[r] = qz;
    for (int k4 = 0; k4 < 32; ++k4) {
      const float4 wv = WqP[k4 * 128 + c];
      #pragma unroll
      for (int r = 0; r < 4; ++r)
        qreg[r] = dot4(((const float4*)dsth[r])[k4], wv, qreg[r]);
    }
  }

  float m[4], lsum[4], ag[4];
  #pragma unroll
  for (int r = 0; r < 4; ++r) { m[r] = -1e30f; lsum[r] = 0.f; ag[r] = 0.f; }

  for (int kk = 0; kk < K_; ++kk) {
    #pragma unroll
    for (int r = 0; r < 4; ++r) {
      const size_t row = (size_t)((i0 + r) * K_ + kk);
      const float kf = bf2f(KVb[row * 256 + c]);
      const float vf = bf2f(KVb[row * 256 + 128 + c]);
      float p = qreg[r] * kf;
      for (int s = 32; s; s >>= 1) p += __shfl_xor(p, s);   // per-head (=wave) reduce
      const float mn = fmaxf(m[r], p);
      const float sc = expf(m[r] - mn);
      const float e  = expf(p - mn);
      lsum[r] = lsum[r] * sc + e;
      ag[r]   = ag[r] * sc + e * vf;
      m[r]    = mn;
    }
  }
  for (int r = 0; r < 4; ++r) aggl[r][c] = ag[r] / lsum[r];
  __syncthreads();

  float oacc[4];
  {
    const float boc = bo[c];
    #pragma unroll
    for (int r = 0; r < 4; ++r) oacc[r] = boc;
    for (int k4 = 0; k4 < 32; ++k4) {
      const float4 wv = WoP[k4 * 128 + c];
      #pragma unroll
      for (int r = 0; r < 4; ++r)
        oacc[r] = dot4(((const float4*)dsth[r])[k4], wv, oacc[r]);
    }
    for (int k4 = 0; k4 < 32; ++k4) {
      const float4 wv = WoP[(32 + k4) * 128 + c];
      #pragma unroll
      for (int r = 0; r < 4; ++r)
        oacc[r] = dot4(((const float4*)aggl[r])[k4], wv, oacc[r]);
    }
  }
  #pragma unroll
  for (int r = 0; r < 4; ++r) {
    const float x = fmaxf(oacc[r], 0.f);
    float s = x, q2 = x * x;
    for (int t = 32; t; t >>= 1) { s += __shfl_xor(s, t); q2 += __shfl_xor(q2, t); }
    if ((c & 63) == 0) { redS[wave][r] = s; redQ[wave][r] = q2; }
  }
  __syncthreads();
  const float lng = ln_g[c], lnb = ln_b[c];
  for (int r = 0; r < 4; ++r) {
    const float sum = redS[0][r] + redS[1][r];
    const float sq  = redQ[0][r] + redQ[1][r];
    const float mu  = sum * (1.0f / 128.0f);
    const float var = sq * (1.0f / 128.0f) - mu * mu;
    const float x   = fmaxf(oacc[r], 0.f);
    emb[(size_t)(i0 + r) * 128 + c] = lng * (x - mu) * rsqrtf(var + 1e-5f) + lnb;
  }
}

// ---------------- k3: edge predictor -> out[B][2] ----------------
__global__ __launch_bounds__(128) void k3_ep(
    const float* __restrict__ emb, const float4* __restrict__ SwP,
    const float4* __restrict__ DwP, const float* __restrict__ ep_sb,
    const float* __restrict__ ep_db, const float* __restrict__ ep_ow,
    const float* __restrict__ ep_ob, float* __restrict__ out)
{
  __shared__ float se[128], de[128], ne[128];
  __shared__ float redp[2], redn[2];
  const int c = threadIdx.x;
  const int i = blockIdx.x;
  se[c] = emb[(size_t)i * 128 + c];
  de[c] = emb[(size_t)(B_ + i) * 128 + c];
  ne[c] = emb[(size_t)(2 * B_ + i) * 128 + c];
  __syncthreads();
  float sacc = ep_sb[c], dacc = ep_db[c], nacc = ep_db[c];
  for (int k4 = 0; k4 < 32; ++k4) {
    const float4 sw = SwP[k4 * 128 + c];
    const float4 dw = DwP[k4 * 128 + c];
    sacc = dot4(((const float4*)se)[k4], sw, sacc);
    dacc = dot4(((const float4*)de)[k4], dw, dacc);
    nacc = dot4(((const float4*)ne)[k4], dw, nacc);
  }
  const float ow = ep_ow[c];
  float pp = fmaxf(sacc + dacc, 0.f) * ow;
  float pn = fmaxf(sacc + nacc, 0.f) * ow;
  for (int t = 32; t; t >>= 1) { pp += __shfl_xor(pp, t); pn += __shfl_xor(pn, t); }
  if ((c & 63) == 0) { redp[c >> 6] = pp; redn[c >> 6] = pn; }
  __syncthreads();
  if (c == 0) {
    const float ob = ep_ob[0];
    out[i * 2]     = redp[0] + redp[1] + ob;
    out[i * 2 + 1] = redn[0] + redn[1] + ob;
  }
}

// ---------------- launch ----------------
extern "C" void kernel_launch(void* const* d_in, const int* in_sizes, int n_in,
                              void* d_out, int out_size, void* d_ws, size_t ws_size,
                              hipStream_t stream) {
  const int*   nodes     = (const int*)d_in[0];
  const int*   eids      = (const int*)d_in[1];
  const float* dt_nbr    = (const float*)d_in[2];
  const float* nfeat     = (const float*)d_in[3];
  const float* mem_data  = (const float*)d_in[4];
  const float* mem_time  = (const float*)d_in[5];
  const float* mail_data = (const float*)d_in[6];
  const float* mail_time = (const float*)d_in[7];
  const float* efeat     = (const float*)d_in[8];
  const float* time_w    = (const float*)d_in[9];
  const float* time_b    = (const float*)d_in[10];
  const float* gru_w_ih  = (const float*)d_in[11];
  const float* gru_w_hh  = (const float*)d_in[12];
  const float* gru_b_ih  = (const float*)d_in[13];
  const float* gru_b_hh  = (const float*)d_in[14];
  const float* wq        = (const float*)d_in[15];
  const float* bq        = (const float*)d_in[16];
  const float* wk        = (const float*)d_in[17];
  const float* bk        = (const float*)d_in[18];
  const float* wv        = (const float*)d_in[19];
  const float* bv        = (const float*)d_in[20];
  const float* wo        = (const float*)d_in[21];
  const float* bo        = (const float*)d_in[22];
  const float* ln_g      = (const float*)d_in[23];
  const float* ln_b      = (const float*)d_in[24];
  const float* ep_sw     = (const float*)d_in[25];
  const float* ep_sb     = (const float*)d_in[26];
  const float* ep_dw     = (const float*)d_in[27];
  const float* ep_db     = (const float*)d_in[28];
  const float* ep_ow     = (const float*)d_in[29];
  const float* ep_ob     = (const float*)d_in[30];
  float* out = (float*)d_out;
  float* ws  = (float*)d_ws;

  unsigned short* hb    = (unsigned short*)(ws + OFF_HB);
  unsigned short* KVb   = (unsigned short*)(ws + OFF_KV);
  float*          emb   = ws + OFF_EMB;
  unsigned short* WcatP = (unsigned short*)(ws + OFF_WCAT);
  unsigned short* WkvP  = (unsigned short*)(ws + OFF_WKV);
  float*          bcat  = ws + OFF_BCAT;
  float*          bkv   = ws + OFF_BKV;
  float4*         WqP   = (float4*)(ws + OFF_WQP);
  float4*         WoP   = (float4*)(ws + OFF_WOP);
  float4*         SwP   = (float4*)(ws + OFF_SWP);
  float4*         DwP   = (float4*)(ws + OFF_DWP);
  float*          qzero = ws + OFF_QZ;

  k0_packWcat<<<1280, 256, 0, stream>>>(gru_w_ih, gru_w_hh, WcatP);
  k0_packWkv<<<192 * 2, 256, 0, stream>>>(wk, wv, WkvP);   // 384 blocks
  k0_misc<<<83, 256, 0, stream>>>(wq, wo, ep_sw, ep_dw, gru_b_ih, gru_b_hh, bk, bv,
                                  WqP, WoP, SwP, DwP, bcat, bkv);
  k0_qzero<<<1, 128, 0, stream>>>(time_b, wq, bq, qzero);

  k1_gru<<<NTOT / 32, 256, 0, stream>>>(nodes, nfeat, mem_data, mem_time, mail_data,
                                        mail_time, time_w, time_b, WcatP, bcat, hb);
  k2a_kv<<<RKV / 32, 256, 0, stream>>>(hb, eids, dt_nbr, efeat, time_w, time_b,
                                       WkvP, bkv, KVb);
  k2b_att<<<ND_ / 4, 128, 0, stream>>>(hb, KVb, qzero, WqP, WoP, bo, ln_g, ln_b, emb);
  k3_ep<<<B_, 128, 0, stream>>>(emb, SwP, DwP, ep_sb, ep_db, ep_ow, ep_ob, out);
}

// Round 3
// 1063.996 us; speedup vs baseline: 2.3013x; 1.1453x over previous
//
#include <hip/hip_runtime.h>

// ---------------- problem constants ----------------
constexpr int ND_   = 12288;           // 3*B
constexpr int K_    = 10;
constexpr int NTOT  = ND_ * (1 + K_);  // 135168
constexpr int B_    = 4096;
constexpr int RKV   = ND_ * K_;        // 122880

constexpr int CH1   = NTOT / 4;        // 33792 rows per GRU chunk
constexpr int CH2   = RKV / 4;         // 30720 rows per KV chunk

// ---------------- ws layout (float offsets) ----------------
// Overlap region holds Abuf (chunk, ushort[CH1*640] = 10,813,440 fl) or
// KVin (chunk, ushort[CH2*384] = 5,898,240 fl) — never live simultaneously.
constexpr size_t OFF_OVL  = 0;
constexpr size_t OFF_HB   = 10813440;   // ushort[NTOT*128] -> 8,650,752 fl
constexpr size_t OFF_KVB  = 19464192;   // ushort[RKV*256]  -> 15,728,640 fl
constexpr size_t OFF_EMB  = 35192832;   // float[ND_*128]   -> 1,572,864
constexpr size_t OFF_WCAT = 36765696;   // ushort[640*512]  -> 163,840 fl
constexpr size_t OFF_WKV  = 36929536;   // ushort[384*256]  -> 49,152 fl
constexpr size_t OFF_BCAT = 36978688;   // float[512]
constexpr size_t OFF_BKV  = 36979200;   // float[256]
constexpr size_t OFF_WQP  = 36979456;   // float4[32*128]
constexpr size_t OFF_WOP  = 36995840;   // float4[64*128]
constexpr size_t OFF_SWP  = 37028608;   // float4[32*128]
constexpr size_t OFF_DWP  = 37044992;   // float4[32*128]
constexpr size_t OFF_QZ   = 37061376;   // float[128]
// total ~37,061,504 floats = 148.2 MB

#define DEVFN __device__ __forceinline__

typedef __attribute__((ext_vector_type(8))) short bf16x8;
typedef __attribute__((ext_vector_type(4))) float f32x4;
#define MFMA16(a, b, c) __builtin_amdgcn_mfma_f32_16x16x32_bf16((a), (b), (c), 0, 0, 0)

DEVFN unsigned short f2bf(float x) {           // RNE float->bf16
  unsigned int u = __float_as_uint(x);
  u = (u + 0x7FFFu + ((u >> 16) & 1u)) >> 16;
  return (unsigned short)u;
}
DEVFN float bf2f(unsigned short h) { return __uint_as_float(((unsigned int)h) << 16); }

DEVFN float dot4(const float4 a, const float4 b, float acc) {
  acc = fmaf(a.x, b.x, acc);
  acc = fmaf(a.y, b.y, acc);
  acc = fmaf(a.z, b.z, acc);
  acc = fmaf(a.w, b.w, acc);
  return acc;
}
DEVFN float sigmoidf_(float x) { return 1.0f / (1.0f + expf(-x)); }

DEVFN bf16x8 pack8(const float4 a, const float4 b) {
  bf16x8 o;
  o[0] = (short)f2bf(a.x); o[1] = (short)f2bf(a.y);
  o[2] = (short)f2bf(a.z); o[3] = (short)f2bf(a.w);
  o[4] = (short)f2bf(b.x); o[5] = (short)f2bf(b.y);
  o[6] = (short)f2bf(b.z); o[7] = (short)f2bf(b.w);
  return o;
}

// ---------------- k0a: pack Wcat (GRU combined weight) as bf16 MFMA fragments ----------------
// Wcat[k=0..639][c'=0..511]; c' = (j>>5)*128 + g*32 + (j&31), g in {R,Z,Ni,Nh}.
// k<512: w_ih (gates R/Z/Ni; zero Nh); k>=512: w_hh (gates R/Z/Nh; zero Ni).
// Fragment-major: frag f = kt*32 + nt; lane l elem j8 -> k = kt*32+(l>>4)*8+j8, c' = nt*16+(l&15).
__global__ void k0_packWcat(const float* __restrict__ w_ih, const float* __restrict__ w_hh,
                            unsigned short* __restrict__ WcatP)
{
  int gid = blockIdx.x * 256 + threadIdx.x;     // 327,680 total
  int f = gid >> 9, idx = gid & 511;
  int l = idx >> 3, j8 = idx & 7;
  int kt = f >> 5, nt = f & 31;
  int k = kt * 32 + (l >> 4) * 8 + j8;
  int c = nt * 16 + (l & 15);
  int q = c >> 7, g = (c >> 5) & 3, j = q * 32 + (c & 31);
  float w;
  if (g == 0)      w = (k < 512) ? w_ih[(size_t)j * 512 + k]         : w_hh[(size_t)j * 128 + (k - 512)];
  else if (g == 1) w = (k < 512) ? w_ih[(size_t)(128 + j) * 512 + k] : w_hh[(size_t)(128 + j) * 128 + (k - 512)];
  else if (g == 2) w = (k < 512) ? w_ih[(size_t)(256 + j) * 512 + k] : 0.0f;
  else             w = (k < 512) ? 0.0f : w_hh[(size_t)(256 + j) * 128 + (k - 512)];
  WcatP[gid] = f2bf(w);
}

// ---------------- k0b: pack Wkv (K|V) as bf16 fragments (f = kt*16 + nt) ----------------
__global__ void k0_packWkv(const float* __restrict__ wk, const float* __restrict__ wv,
                           unsigned short* __restrict__ WkvP)
{
  int gid = blockIdx.x * 256 + threadIdx.x;     // 98,304 total
  int f = gid >> 9, idx = gid & 511;
  int l = idx >> 3, j8 = idx & 7;
  int kt = f >> 4, nt = f & 15;
  int k = kt * 32 + (l >> 4) * 8 + j8;
  int c = nt * 16 + (l & 15);
  float w = (c < 128) ? wk[(size_t)c * 384 + k] : wv[(size_t)(c - 128) * 384 + k];
  WkvP[gid] = f2bf(w);
}

// ---------------- k0c: misc packs ----------------
__global__ void k0_misc(const float* __restrict__ wq, const float* __restrict__ wo,
                        const float* __restrict__ sw, const float* __restrict__ dwm,
                        const float* __restrict__ b_ih, const float* __restrict__ b_hh,
                        const float* __restrict__ bk, const float* __restrict__ bv,
                        float4* __restrict__ WqP, float4* __restrict__ WoP,
                        float4* __restrict__ SwP, float4* __restrict__ DwP,
                        float* __restrict__ bcat, float* __restrict__ bkv)
{
  int id = blockIdx.x * 256 + threadIdx.x;      // 21,248 total
  if (id < 4096) {
    int k4 = id / 128, c = id % 128;
    const float* s = wq + c * 256 + 4 * k4;
    WqP[id] = make_float4(s[0], s[1], s[2], s[3]);
    return;
  }
  id -= 4096;
  if (id < 8192) {
    int k4 = id / 128, c = id % 128;
    const float* s = wo + c * 256 + 4 * k4;
    WoP[id] = make_float4(s[0], s[1], s[2], s[3]);
    return;
  }
  id -= 8192;
  if (id < 4096) {
    int k4 = id / 128, c = id % 128;
    const float* s = sw + c * 128 + 4 * k4;
    SwP[id] = make_float4(s[0], s[1], s[2], s[3]);
    return;
  }
  id -= 4096;
  if (id < 4096) {
    int k4 = id / 128, c = id % 128;
    const float* s = dwm + c * 128 + 4 * k4;
    DwP[id] = make_float4(s[0], s[1], s[2], s[3]);
    return;
  }
  id -= 4096;
  if (id < 512) {
    int q = id >> 7, g = (id >> 5) & 3, j = q * 32 + (id & 31);
    float b;
    if (g == 0)      b = b_ih[j] + b_hh[j];
    else if (g == 1) b = b_ih[128 + j] + b_hh[128 + j];
    else if (g == 2) b = b_ih[256 + j];
    else             b = b_hh[256 + j];
    bcat[id] = b;
    return;
  }
  id -= 512;
  if (id < 256) bkv[id] = (id < 128) ? bk[id] : bv[id - 128];
}

// qzero[c] = bq[c] + sum_k cos(time_b[k]) * wq[c][128+k]
__global__ void k0_qzero(const float* __restrict__ time_b, const float* __restrict__ wq,
                         const float* __restrict__ bq, float* __restrict__ qzero)
{
  int c = threadIdx.x;
  float acc = bq[c];
  for (int k = 0; k < 128; ++k)
    acc = fmaf(cosf(time_b[k]), wq[c * 256 + 128 + k], acc);
  qzero[c] = acc;
}

// ---------------- kA: build Abuf (chunk) in A-fragment-major bf16 ----------------
// Abuf elem index = ((t16*20)+kt)*512 + l*8 + j  <=  source (row = t16*16+(l&15),
// col = kt*32+(l>>4)*8+j) of [mail(384)|tenc(128)|mem(128)].
__global__ __launch_bounds__(256) void kA_build(
    const int* __restrict__ nodes, const float* __restrict__ mail_data,
    const float* __restrict__ mem_data, const float* __restrict__ mail_time,
    const float* __restrict__ mem_time, const float* __restrict__ time_w,
    const float* __restrict__ time_b, unsigned short* __restrict__ Abuf, int row0)
{
  const int w = threadIdx.x >> 6, l = threadIdx.x & 63;
  const int t16 = blockIdx.x * 4 + w;
  const int lr = l >> 4, lc = l & 15;
  int nld = 0; float dld = 0.f;
  if (l < 16) {
    nld = nodes[row0 + t16 * 16 + l];
    dld = mail_time[nld] - mem_time[nld];
  }
  const int   nrow = __shfl(nld, lc);
  const float drow = __shfl(dld, lc);
  const float* mailp = mail_data + (size_t)nrow * 384 + lr * 8;
  const float* memp  = mem_data  + (size_t)nrow * 128 + lr * 8;
  unsigned short* dst = Abuf + (size_t)t16 * (20 * 512) + l * 8;

  #pragma unroll
  for (int kt = 0; kt < 12; ++kt) {
    const float4 v0 = ((const float4*)(mailp + kt * 32))[0];
    const float4 v1 = ((const float4*)(mailp + kt * 32))[1];
    *(bf16x8*)(dst + kt * 512) = pack8(v0, v1);
  }
  #pragma unroll
  for (int kt = 12; kt < 16; ++kt) {
    const int c0 = kt * 32 + lr * 8 - 384;
    const float4 w0 = ((const float4*)(time_w + c0))[0];
    const float4 w1 = ((const float4*)(time_w + c0))[1];
    const float4 b0 = ((const float4*)(time_b + c0))[0];
    const float4 b1 = ((const float4*)(time_b + c0))[1];
    float4 u, v;
    u.x = cosf(fmaf(drow, w0.x, b0.x)); u.y = cosf(fmaf(drow, w0.y, b0.y));
    u.z = cosf(fmaf(drow, w0.z, b0.z)); u.w = cosf(fmaf(drow, w0.w, b0.w));
    v.x = cosf(fmaf(drow, w1.x, b1.x)); v.y = cosf(fmaf(drow, w1.y, b1.y));
    v.z = cosf(fmaf(drow, w1.z, b1.z)); v.w = cosf(fmaf(drow, w1.w, b1.w));
    *(bf16x8*)(dst + kt * 512) = pack8(u, v);
  }
  #pragma unroll
  for (int kt = 16; kt < 20; ++kt) {
    const float4 v0 = ((const float4*)(memp + (kt - 16) * 32))[0];
    const float4 v1 = ((const float4*)(memp + (kt - 16) * 32))[1];
    *(bf16x8*)(dst + kt * 512) = pack8(v0, v1);
  }
}

// ---------------- k1_gemm: barrier-free MFMA GEMM + GRU epilogue ----------------
// 512 thr = 8 waves (wm 2 x wn 4); BM=64 rows/block; per wave 2 m-tiles x 8 n-tiles.
DEVFN void ldk1(const unsigned short* Ap0, const unsigned short* Ap1,
                const unsigned short* Bp, int kt, bf16x8 (&A)[2], bf16x8 (&B)[8]) {
  A[0] = *(const bf16x8*)(Ap0 + (size_t)kt * 512);
  A[1] = *(const bf16x8*)(Ap1 + (size_t)kt * 512);
  #pragma unroll
  for (int bn = 0; bn < 8; ++bn)
    B[bn] = *(const bf16x8*)(Bp + ((size_t)kt * 32 + bn) * 512);
}
DEVFN void mmk1(f32x4 (&acc)[2][8], const bf16x8 (&A)[2], const bf16x8 (&B)[8]) {
  #pragma unroll
  for (int bn = 0; bn < 8; ++bn) {
    acc[0][bn] = MFMA16(A[0], B[bn], acc[0][bn]);
    acc[1][bn] = MFMA16(A[1], B[bn], acc[1][bn]);
  }
}

__global__ __launch_bounds__(512) void k1_gemm(
    const unsigned short* __restrict__ Abuf, const unsigned short* __restrict__ WcatP,
    const float* __restrict__ bcat, const int* __restrict__ nodes,
    const float* __restrict__ nfeat, unsigned short* __restrict__ hb, int row0)
{
  const int w = threadIdx.x >> 6, l = threadIdx.x & 63;
  const int wm = w >> 2, wn = w & 3;
  const int lr = l >> 4, lc = l & 15;
  const int t16base = blockIdx.x * 4 + wm * 2;
  const unsigned short* Ap0 = Abuf + (size_t)t16base * (20 * 512) + l * 8;
  const unsigned short* Ap1 = Ap0 + 20 * 512;
  const unsigned short* Bp  = WcatP + (size_t)(wn * 8) * 512 + l * 8;

  f32x4 acc[2][8];
  #pragma unroll
  for (int m = 0; m < 2; ++m)
    #pragma unroll
    for (int bn = 0; bn < 8; ++bn) acc[m][bn] = (f32x4){0.f, 0.f, 0.f, 0.f};

  bf16x8 A0[2], A1[2], B0[8], B1[8];
  ldk1(Ap0, Ap1, Bp, 0, A0, B0);
  for (int kt = 0; kt < 20; kt += 2) {
    ldk1(Ap0, Ap1, Bp, kt + 1, A1, B1);
    mmk1(acc, A0, B0);
    if (kt + 2 < 20) ldk1(Ap0, Ap1, Bp, kt + 2, A0, B0);
    mmk1(acc, A1, B1);
  }

  // GRU epilogue: nt = wn*8+bn -> gate g=bn>>1, jb=bn&1, j = wn*32+jb*16+lc
  float bg[4][2];
  #pragma unroll
  for (int g = 0; g < 4; ++g)
    #pragma unroll
    for (int jb = 0; jb < 2; ++jb) bg[g][jb] = bcat[wn * 128 + (g * 2 + jb) * 16 + lc];

  #pragma unroll
  for (int mt = 0; mt < 2; ++mt) {
    const int t16 = t16base + mt;
    #pragma unroll
    for (int rr = 0; rr < 4; ++rr) {
      const int rloc16 = lr * 4 + rr;
      const int grow   = row0 + t16 * 16 + rloc16;
      const int n      = nodes[grow];
      #pragma unroll
      for (int jb = 0; jb < 2; ++jb) {
        const int j = wn * 32 + jb * 16 + lc;
        const float aR  = acc[mt][0 + jb][rr] + bg[0][jb];
        const float aZ  = acc[mt][2 + jb][rr] + bg[1][jb];
        const float aNi = acc[mt][4 + jb][rr] + bg[2][jb];
        const float aNh = acc[mt][6 + jb][rr] + bg[3][jb];
        const float r_  = sigmoidf_(aR);
        const float z_  = sigmoidf_(aZ);
        const float n_  = tanhf(aNi + r_ * aNh);
        const int ke = jb * 16 + lc;   // mem col within kt=16+wn tile
        const float mem = bf2f(Abuf[((size_t)t16 * 20 + 16 + wn) * 512 +
                                    ((ke >> 3) * 16 + rloc16) * 8 + (ke & 7)]);
        const float h = nfeat[(size_t)n * 128 + j] + (1.0f - z_) * n_ + z_ * mem;
        hb[(size_t)grow * 128 + j] = f2bf(h);
      }
    }
  }
}

// ---------------- kB: build KVin (chunk) fragment-major bf16 ----------------
// cols: [src_h(128, already bf16) | efeat(128) | tenc(128)]; 12 kt tiles.
__global__ __launch_bounds__(256) void kB_build(
    const unsigned short* __restrict__ hb, const int* __restrict__ eids,
    const float* __restrict__ dt_nbr, const float* __restrict__ efeat,
    const float* __restrict__ time_w, const float* __restrict__ time_b,
    unsigned short* __restrict__ KVin, int row0)
{
  const int w = threadIdx.x >> 6, l = threadIdx.x & 63;
  const int t16 = blockIdx.x * 4 + w;
  const int lr = l >> 4, lc = l & 15;
  int eld = 0; float dld = 0.f;
  if (l < 16) {
    eld = eids[row0 + t16 * 16 + l];
    dld = dt_nbr[row0 + t16 * 16 + l];
  }
  const int   eid = __shfl(eld, lc);
  const float dt  = __shfl(dld, lc);
  const unsigned short* hbp = hb + (size_t)(ND_ + row0 + t16 * 16 + lc) * 128 + lr * 8;
  const float* efp = efeat + (size_t)eid * 128 + lr * 8;
  unsigned short* dst = KVin + (size_t)t16 * (12 * 512) + l * 8;

  #pragma unroll
  for (int kt = 0; kt < 4; ++kt)
    *(bf16x8*)(dst + kt * 512) = *(const bf16x8*)(hbp + kt * 32);
  #pragma unroll
  for (int kt = 4; kt < 8; ++kt) {
    const float4 v0 = ((const float4*)(efp + (kt - 4) * 32))[0];
    const float4 v1 = ((const float4*)(efp + (kt - 4) * 32))[1];
    *(bf16x8*)(dst + kt * 512) = pack8(v0, v1);
  }
  #pragma unroll
  for (int kt = 8; kt < 12; ++kt) {
    const int c0 = kt * 32 + lr * 8 - 256;
    const float4 w0 = ((const float4*)(time_w + c0))[0];
    const float4 w1 = ((const float4*)(time_w + c0))[1];
    const float4 b0 = ((const float4*)(time_b + c0))[0];
    const float4 b1 = ((const float4*)(time_b + c0))[1];
    float4 u, v;
    u.x = cosf(fmaf(dt, w0.x, b0.x)); u.y = cosf(fmaf(dt, w0.y, b0.y));
    u.z = cosf(fmaf(dt, w0.z, b0.z)); u.w = cosf(fmaf(dt, w0.w, b0.w));
    v.x = cosf(fmaf(dt, w1.x, b1.x)); v.y = cosf(fmaf(dt, w1.y, b1.y));
    v.z = cosf(fmaf(dt, w1.z, b1.z)); v.w = cosf(fmaf(dt, w1.w, b1.w));
    *(bf16x8*)(dst + kt * 512) = pack8(u, v);
  }
}

// ---------------- k2_gemm: KV projection GEMM -> KVb ----------------
DEVFN void ldk2(const unsigned short* Ap0, const unsigned short* Ap1,
                const unsigned short* Bp, int kt, bf16x8 (&A)[2], bf16x8 (&B)[4]) {
  A[0] = *(const bf16x8*)(Ap0 + (size_t)kt * 512);
  A[1] = *(const bf16x8*)(Ap1 + (size_t)kt * 512);
  #pragma unroll
  for (int bn = 0; bn < 4; ++bn)
    B[bn] = *(const bf16x8*)(Bp + ((size_t)kt * 16 + bn) * 512);
}
DEVFN void mmk2(f32x4 (&acc)[2][4], const bf16x8 (&A)[2], const bf16x8 (&B)[4]) {
  #pragma unroll
  for (int bn = 0; bn < 4; ++bn) {
    acc[0][bn] = MFMA16(A[0], B[bn], acc[0][bn]);
    acc[1][bn] = MFMA16(A[1], B[bn], acc[1][bn]);
  }
}

__global__ __launch_bounds__(512) void k2_gemm(
    const unsigned short* __restrict__ KVin, const unsigned short* __restrict__ WkvP,
    const float* __restrict__ bkv, unsigned short* __restrict__ KVb, int row0)
{
  const int w = threadIdx.x >> 6, l = threadIdx.x & 63;
  const int wm = w >> 2, wn = w & 3;
  const int lr = l >> 4, lc = l & 15;
  const int t16base = blockIdx.x * 4 + wm * 2;
  const unsigned short* Ap0 = KVin + (size_t)t16base * (12 * 512) + l * 8;
  const unsigned short* Ap1 = Ap0 + 12 * 512;
  const unsigned short* Bp  = WkvP + (size_t)(wn * 4) * 512 + l * 8;

  f32x4 acc[2][4];
  #pragma unroll
  for (int m = 0; m < 2; ++m)
    #pragma unroll
    for (int bn = 0; bn < 4; ++bn) acc[m][bn] = (f32x4){0.f, 0.f, 0.f, 0.f};

  bf16x8 A0[2], A1[2], B0[4], B1[4];
  ldk2(Ap0, Ap1, Bp, 0, A0, B0);
  for (int kt = 0; kt < 12; kt += 2) {
    ldk2(Ap0, Ap1, Bp, kt + 1, A1, B1);
    mmk2(acc, A0, B0);
    if (kt + 2 < 12) ldk2(Ap0, Ap1, Bp, kt + 2, A0, B0);
    mmk2(acc, A1, B1);
  }

  float bb[4];
  #pragma unroll
  for (int bn = 0; bn < 4; ++bn) bb[bn] = bkv[wn * 64 + bn * 16 + lc];

  #pragma unroll
  for (int mt = 0; mt < 2; ++mt) {
    const int t16 = t16base + mt;
    #pragma unroll
    for (int rr = 0; rr < 4; ++rr) {
      const size_t grow = (size_t)(row0 + t16 * 16 + lr * 4 + rr);
      #pragma unroll
      for (int bn = 0; bn < 4; ++bn)
        KVb[grow * 256 + wn * 64 + bn * 16 + lc] = f2bf(acc[mt][bn][rr] + bb[bn]);
    }
  }
}

// ---------------- k2b: Q + attention + out-proj + LN -> emb (fp32) ----------------
__global__ __launch_bounds__(128) void k2b_att(
    const unsigned short* __restrict__ hb, const unsigned short* __restrict__ KVb,
    const float* __restrict__ qzero, const float4* __restrict__ WqP,
    const float4* __restrict__ WoP, const float* __restrict__ bo,
    const float* __restrict__ ln_g, const float* __restrict__ ln_b,
    float* __restrict__ emb)
{
  __shared__ float dsth[4][128];
  __shared__ float aggl[4][128];
  __shared__ float redS[2][4], redQ[2][4];
  const int c = threadIdx.x;
  const int wave = c >> 6;
  const int i0 = blockIdx.x * 4;

  for (int r = 0; r < 4; ++r) dsth[r][c] = bf2f(hb[(size_t)(i0 + r) * 128 + c]);
  __syncthreads();

  float qreg[4];
  {
    const float qz = qzero[c];
    #pragma unroll
    for (int r = 0; r < 4; ++r) qreg[r] = qz;
    for (int k4 = 0; k4 < 32; ++k4) {
      const float4 wv = WqP[k4 * 128 + c];
      #pragma unroll
      for (int r = 0; r < 4; ++r)
        qreg[r] = dot4(((const float4*)dsth[r])[k4], wv, qreg[r]);
    }
  }

  float m[4], lsum[4], ag[4];
  #pragma unroll
  for (int r = 0; r < 4; ++r) { m[r] = -1e30f; lsum[r] = 0.f; ag[r] = 0.f; }

  for (int kk = 0; kk < K_; ++kk) {
    #pragma unroll
    for (int r = 0; r < 4; ++r) {
      const size_t row = (size_t)((i0 + r) * K_ + kk);
      const float kf = bf2f(KVb[row * 256 + c]);
      const float vf = bf2f(KVb[row * 256 + 128 + c]);
      float p = qreg[r] * kf;
      for (int s = 32; s; s >>= 1) p += __shfl_xor(p, s);
      const float mn = fmaxf(m[r], p);
      const float sc = expf(m[r] - mn);
      const float e  = expf(p - mn);
      lsum[r] = lsum[r] * sc + e;
      ag[r]   = ag[r] * sc + e * vf;
      m[r]    = mn;
    }
  }
  for (int r = 0; r < 4; ++r) aggl[r][c] = ag[r] / lsum[r];
  __syncthreads();

  float oacc[4];
  {
    const float boc = bo[c];
    #pragma unroll
    for (int r = 0; r < 4; ++r) oacc[r] = boc;
    for (int k4 = 0; k4 < 32; ++k4) {
      const float4 wv = WoP[k4 * 128 + c];
      #pragma unroll
      for (int r = 0; r < 4; ++r)
        oacc[r] = dot4(((const float4*)dsth[r])[k4], wv, oacc[r]);
    }
    for (int k4 = 0; k4 < 32; ++k4) {
      const float4 wv = WoP[(32 + k4) * 128 + c];
      #pragma unroll
      for (int r = 0; r < 4; ++r)
        oacc[r] = dot4(((const float4*)aggl[r])[k4], wv, oacc[r]);
    }
  }
  #pragma unroll
  for (int r = 0; r < 4; ++r) {
    const float x = fmaxf(oacc[r], 0.f);
    float s = x, q2 = x * x;
    for (int t = 32; t; t >>= 1) { s += __shfl_xor(s, t); q2 += __shfl_xor(q2, t); }
    if ((c & 63) == 0) { redS[wave][r] = s; redQ[wave][r] = q2; }
  }
  __syncthreads();
  const float lng = ln_g[c], lnb = ln_b[c];
  for (int r = 0; r < 4; ++r) {
    const float sum = redS[0][r] + redS[1][r];
    const float sq  = redQ[0][r] + redQ[1][r];
    const float mu  = sum * (1.0f / 128.0f);
    const float var = sq * (1.0f / 128.0f) - mu * mu;
    const float x   = fmaxf(oacc[r], 0.f);
    emb[(size_t)(i0 + r) * 128 + c] = lng * (x - mu) * rsqrtf(var + 1e-5f) + lnb;
  }
}

// ---------------- k3: edge predictor -> out[B][2] ----------------
__global__ __launch_bounds__(128) void k3_ep(
    const float* __restrict__ emb, const float4* __restrict__ SwP,
    const float4* __restrict__ DwP, const float* __restrict__ ep_sb,
    const float* __restrict__ ep_db, const float* __restrict__ ep_ow,
    const float* __restrict__ ep_ob, float* __restrict__ out)
{
  __shared__ float se[128], de[128], ne[128];
  __shared__ float redp[2], redn[2];
  const int c = threadIdx.x;
  const int i = blockIdx.x;
  se[c] = emb[(size_t)i * 128 + c];
  de[c] = emb[(size_t)(B_ + i) * 128 + c];
  ne[c] = emb[(size_t)(2 * B_ + i) * 128 + c];
  __syncthreads();
  float sacc = ep_sb[c], dacc = ep_db[c], nacc = ep_db[c];
  for (int k4 = 0; k4 < 32; ++k4) {
    const float4 sw = SwP[k4 * 128 + c];
    const float4 dw = DwP[k4 * 128 + c];
    sacc = dot4(((const float4*)se)[k4], sw, sacc);
    dacc = dot4(((const float4*)de)[k4], dw, dacc);
    nacc = dot4(((const float4*)ne)[k4], dw, nacc);
  }
  const float ow = ep_ow[c];
  float pp = fmaxf(sacc + dacc, 0.f) * ow;
  float pn = fmaxf(sacc + nacc, 0.f) * ow;
  for (int t = 32; t; t >>= 1) { pp += __shfl_xor(pp, t); pn += __shfl_xor(pn, t); }
  if ((c & 63) == 0) { redp[c >> 6] = pp; redn[c >> 6] = pn; }
  __syncthreads();
  if (c == 0) {
    const float ob = ep_ob[0];
    out[i * 2]     = redp[0] + redp[1] + ob;
    out[i * 2 + 1] = redn[0] + redn[1] + ob;
  }
}

// ---------------- launch ----------------
extern "C" void kernel_launch(void* const* d_in, const int* in_sizes, int n_in,
                              void* d_out, int out_size, void* d_ws, size_t ws_size,
                              hipStream_t stream) {
  const int*   nodes     = (const int*)d_in[0];
  const int*   eids      = (const int*)d_in[1];
  const float* dt_nbr    = (const float*)d_in[2];
  const float* nfeat     = (const float*)d_in[3];
  const float* mem_data  = (const float*)d_in[4];
  const float* mem_time  = (const float*)d_in[5];
  const float* mail_data = (const float*)d_in[6];
  const float* mail_time = (const float*)d_in[7];
  const float* efeat     = (const float*)d_in[8];
  const float* time_w    = (const float*)d_in[9];
  const float* time_b    = (const float*)d_in[10];
  const float* gru_w_ih  = (const float*)d_in[11];
  const float* gru_w_hh  = (const float*)d_in[12];
  const float* gru_b_ih  = (const float*)d_in[13];
  const float* gru_b_hh  = (const float*)d_in[14];
  const float* wq        = (const float*)d_in[15];
  const float* bq        = (const float*)d_in[16];
  const float* wk        = (const float*)d_in[17];
  const float* bk        = (const float*)d_in[18];
  const float* wv        = (const float*)d_in[19];
  const float* bv        = (const float*)d_in[20];
  const float* wo        = (const float*)d_in[21];
  const float* bo        = (const float*)d_in[22];
  const float* ln_g      = (const float*)d_in[23];
  const float* ln_b      = (const float*)d_in[24];
  const float* ep_sw     = (const float*)d_in[25];
  const float* ep_sb     = (const float*)d_in[26];
  const float* ep_dw     = (const float*)d_in[27];
  const float* ep_db     = (const float*)d_in[28];
  const float* ep_ow     = (const float*)d_in[29];
  const float* ep_ob     = (const float*)d_in[30];
  float* out = (float*)d_out;
  float* ws  = (float*)d_ws;

  unsigned short* OVL   = (unsigned short*)(ws + OFF_OVL);   // Abuf / KVin chunks
  unsigned short* hb    = (unsigned short*)(ws + OFF_HB);
  unsigned short* KVb   = (unsigned short*)(ws + OFF_KVB);
  float*          emb   = ws + OFF_EMB;
  unsigned short* WcatP = (unsigned short*)(ws + OFF_WCAT);
  unsigned short* WkvP  = (unsigned short*)(ws + OFF_WKV);
  float*          bcat  = ws + OFF_BCAT;
  float*          bkv   = ws + OFF_BKV;
  float4*         WqP   = (float4*)(ws + OFF_WQP);
  float4*         WoP   = (float4*)(ws + OFF_WOP);
  float4*         SwP   = (float4*)(ws + OFF_SWP);
  float4*         DwP   = (float4*)(ws + OFF_DWP);
  float*          qzero = ws + OFF_QZ;

  k0_packWcat<<<1280, 256, 0, stream>>>(gru_w_ih, gru_w_hh, WcatP);
  k0_packWkv<<<384, 256, 0, stream>>>(wk, wv, WkvP);
  k0_misc<<<83, 256, 0, stream>>>(wq, wo, ep_sw, ep_dw, gru_b_ih, gru_b_hh, bk, bv,
                                  WqP, WoP, SwP, DwP, bcat, bkv);
  k0_qzero<<<1, 128, 0, stream>>>(time_b, wq, bq, qzero);

  for (int c = 0; c < 4; ++c) {
    kA_build<<<CH1 / 64, 256, 0, stream>>>(nodes, mail_data, mem_data, mail_time,
                                           mem_time, time_w, time_b, OVL, c * CH1);
    k1_gemm<<<CH1 / 64, 512, 0, stream>>>(OVL, WcatP, bcat, nodes, nfeat, hb, c * CH1);
  }
  for (int c = 0; c < 4; ++c) {
    kB_build<<<CH2 / 64, 256, 0, stream>>>(hb, eids, dt_nbr, efeat, time_w, time_b,
                                           OVL, c * CH2);
    k2_gemm<<<CH2 / 64, 512, 0, stream>>>(OVL, WkvP, bkv, KVb, c * CH2);
  }
  k2b_att<<<ND_ / 4, 128, 0, stream>>>(hb, KVb, qzero, WqP, WoP, bo, ln_g, ln_b, emb);
  k3_ep<<<B_, 128, 0, stream>>>(emb, SwP, DwP, ep_sb, ep_db, ep_ow, ep_ob, out);
}

// Round 4
// 594.574 us; speedup vs baseline: 4.1182x; 1.7895x over previous
//
#include <hip/hip_runtime.h>

// ---------------- problem constants ----------------
constexpr int ND_   = 12288;           // 3*B
constexpr int K_    = 10;
constexpr int NTOT  = ND_ * (1 + K_);  // 135168
constexpr int B_    = 4096;
constexpr int RKV   = ND_ * K_;        // 122880

constexpr int CH1   = NTOT / 4;        // 33792 rows per GRU chunk
constexpr int CH2   = RKV / 4;         // 30720 rows per KV chunk

// ---------------- ws layout (float offsets) ----------------
// OVL region: Abuf chunk (10.8M fl) / KVin chunk (5.9M fl) during the GEMM loops,
// then reused for Qb / aggb / OutR in the attention stage (never simultaneous).
constexpr size_t OFF_OVL  = 0;
constexpr size_t OFF_QB   = 0;          // ushort[ND_*128]  ->   786,432 fl
constexpr size_t OFF_AGG  = 786432;     // ushort[ND_*128]  ->   786,432 fl
constexpr size_t OFF_OUTR = 1572864;    // float [ND_*128]  -> 1,572,864 fl
constexpr size_t OFF_HB   = 10813440;   // ushort[NTOT*128] -> 8,650,752 fl
constexpr size_t OFF_KVB  = 19464192;   // ushort[RKV*256]  -> 15,728,640 fl
constexpr size_t OFF_EMB  = 35192832;   // float[ND_*128]   -> 1,572,864
constexpr size_t OFF_WCAT = 36765696;   // ushort[640*512]  -> 163,840 fl
constexpr size_t OFF_WKV  = 36929536;   // ushort[384*256]  -> 49,152 fl
constexpr size_t OFF_BCAT = 36978688;   // float[512]
constexpr size_t OFF_BKV  = 36979200;   // float[256]
constexpr size_t OFF_WQB  = 36979456;   // ushort[128*128]  -> 8,192 fl
constexpr size_t OFF_WOB  = 36995840;   // ushort[256*128]  -> 16,384 fl
constexpr size_t OFF_SWP  = 37028608;   // float4[32*128]
constexpr size_t OFF_DWP  = 37044992;   // float4[32*128]
constexpr size_t OFF_QZ   = 37061376;   // float[128]
// total ~37,061,504 floats = 148.2 MB (same as round 3)

#define DEVFN __device__ __forceinline__

typedef __attribute__((ext_vector_type(8))) short bf16x8;
typedef __attribute__((ext_vector_type(4))) float f32x4;
#define MFMA16(a, b, c) __builtin_amdgcn_mfma_f32_16x16x32_bf16((a), (b), (c), 0, 0, 0)

DEVFN unsigned short f2bf(float x) {           // RNE float->bf16
  unsigned int u = __float_as_uint(x);
  u = (u + 0x7FFFu + ((u >> 16) & 1u)) >> 16;
  return (unsigned short)u;
}
DEVFN float bf2f(unsigned short h) { return __uint_as_float(((unsigned int)h) << 16); }

DEVFN float dot4(const float4 a, const float4 b, float acc) {
  acc = fmaf(a.x, b.x, acc);
  acc = fmaf(a.y, b.y, acc);
  acc = fmaf(a.z, b.z, acc);
  acc = fmaf(a.w, b.w, acc);
  return acc;
}
DEVFN float sigmoidf_(float x) { return 1.0f / (1.0f + expf(-x)); }

DEVFN bf16x8 pack8(const float4 a, const float4 b) {
  bf16x8 o;
  o[0] = (short)f2bf(a.x); o[1] = (short)f2bf(a.y);
  o[2] = (short)f2bf(a.z); o[3] = (short)f2bf(a.w);
  o[4] = (short)f2bf(b.x); o[5] = (short)f2bf(b.y);
  o[6] = (short)f2bf(b.z); o[7] = (short)f2bf(b.w);
  return o;
}

// ---------------- k0a: pack Wcat (GRU combined weight) as bf16 MFMA fragments ----------------
// Wcat[k=0..639][c'=0..511]; c' = (j>>5)*128 + g*32 + (j&31), g in {R,Z,Ni,Nh}.
// k<512: w_ih (gates R/Z/Ni; zero Nh); k>=512: w_hh (gates R/Z/Nh; zero Ni).
// Fragment-major: frag f = kt*32 + nt; lane l elem j8 -> k = kt*32+(l>>4)*8+j8, c' = nt*16+(l&15).
__global__ void k0_packWcat(const float* __restrict__ w_ih, const float* __restrict__ w_hh,
                            unsigned short* __restrict__ WcatP)
{
  int gid = blockIdx.x * 256 + threadIdx.x;     // 327,680 total
  int f = gid >> 9, idx = gid & 511;
  int l = idx >> 3, j8 = idx & 7;
  int kt = f >> 5, nt = f & 31;
  int k = kt * 32 + (l >> 4) * 8 + j8;
  int c = nt * 16 + (l & 15);
  int q = c >> 7, g = (c >> 5) & 3, j = q * 32 + (c & 31);
  float w;
  if (g == 0)      w = (k < 512) ? w_ih[(size_t)j * 512 + k]         : w_hh[(size_t)j * 128 + (k - 512)];
  else if (g == 1) w = (k < 512) ? w_ih[(size_t)(128 + j) * 512 + k] : w_hh[(size_t)(128 + j) * 128 + (k - 512)];
  else if (g == 2) w = (k < 512) ? w_ih[(size_t)(256 + j) * 512 + k] : 0.0f;
  else             w = (k < 512) ? 0.0f : w_hh[(size_t)(256 + j) * 128 + (k - 512)];
  WcatP[gid] = f2bf(w);
}

// ---------------- k0b: pack Wkv (K|V) as bf16 fragments (f = kt*16 + nt) ----------------
__global__ void k0_packWkv(const float* __restrict__ wk, const float* __restrict__ wv,
                           unsigned short* __restrict__ WkvP)
{
  int gid = blockIdx.x * 256 + threadIdx.x;     // 98,304 total
  int f = gid >> 9, idx = gid & 511;
  int l = idx >> 3, j8 = idx & 7;
  int kt = f >> 4, nt = f & 15;
  int k = kt * 32 + (l >> 4) * 8 + j8;
  int c = nt * 16 + (l & 15);
  float w = (c < 128) ? wk[(size_t)c * 384 + k] : wv[(size_t)(c - 128) * 384 + k];
  WkvP[gid] = f2bf(w);
}

// ---------------- k0q: pack wq(first 128 K) and wo as bf16 fragments (f = kt*8 + nt) ----------------
__global__ void k0_packQO(const float* __restrict__ wq, const float* __restrict__ wo,
                          unsigned short* __restrict__ WqB, unsigned short* __restrict__ WoB)
{
  int gid = blockIdx.x * 256 + threadIdx.x;     // 49,152 total
  if (gid < 16384) {        // WqB: 4 kt x 8 nt
    int f = gid >> 9, idx = gid & 511;
    int l = idx >> 3, j8 = idx & 7;
    int kt = f >> 3, nt = f & 7;
    int k = kt * 32 + (l >> 4) * 8 + j8;
    int c = nt * 16 + (l & 15);
    WqB[gid] = f2bf(wq[(size_t)c * 256 + k]);
    return;
  }
  gid -= 16384;             // WoB: 8 kt x 8 nt
  int f = gid >> 9, idx = gid & 511;
  int l = idx >> 3, j8 = idx & 7;
  int kt = f >> 3, nt = f & 7;
  int k = kt * 32 + (l >> 4) * 8 + j8;
  int c = nt * 16 + (l & 15);
  WoB[gid] = f2bf(wo[(size_t)c * 256 + k]);
}

// ---------------- k0c: misc packs (ep panels + bias vectors) ----------------
__global__ void k0_misc(const float* __restrict__ sw, const float* __restrict__ dwm,
                        const float* __restrict__ b_ih, const float* __restrict__ b_hh,
                        const float* __restrict__ bk, const float* __restrict__ bv,
                        float4* __restrict__ SwP, float4* __restrict__ DwP,
                        float* __restrict__ bcat, float* __restrict__ bkv)
{
  int id = blockIdx.x * 256 + threadIdx.x;      // 8,960 total
  if (id < 4096) {
    int k4 = id / 128, c = id % 128;
    const float* s = sw + c * 128 + 4 * k4;
    SwP[id] = make_float4(s[0], s[1], s[2], s[3]);
    return;
  }
  id -= 4096;
  if (id < 4096) {
    int k4 = id / 128, c = id % 128;
    const float* s = dwm + c * 128 + 4 * k4;
    DwP[id] = make_float4(s[0], s[1], s[2], s[3]);
    return;
  }
  id -= 4096;
  if (id < 512) {
    int q = id >> 7, g = (id >> 5) & 3, j = q * 32 + (id & 31);
    float b;
    if (g == 0)      b = b_ih[j] + b_hh[j];
    else if (g == 1) b = b_ih[128 + j] + b_hh[128 + j];
    else if (g == 2) b = b_ih[256 + j];
    else             b = b_hh[256 + j];
    bcat[id] = b;
    return;
  }
  id -= 512;
  if (id < 256) bkv[id] = (id < 128) ? bk[id] : bv[id - 128];
}

// qzero[c] = bq[c] + sum_k cos(time_b[k]) * wq[c][128+k]
__global__ void k0_qzero(const float* __restrict__ time_b, const float* __restrict__ wq,
                         const float* __restrict__ bq, float* __restrict__ qzero)
{
  int c = threadIdx.x;
  float acc = bq[c];
  for (int k = 0; k < 128; ++k)
    acc = fmaf(cosf(time_b[k]), wq[c * 256 + 128 + k], acc);
  qzero[c] = acc;
}

// ---------------- kA: build Abuf (chunk) in A-fragment-major bf16 ----------------
__global__ __launch_bounds__(256) void kA_build(
    const int* __restrict__ nodes, const float* __restrict__ mail_data,
    const float* __restrict__ mem_data, const float* __restrict__ mail_time,
    const float* __restrict__ mem_time, const float* __restrict__ time_w,
    const float* __restrict__ time_b, unsigned short* __restrict__ Abuf, int row0)
{
  const int w = threadIdx.x >> 6, l = threadIdx.x & 63;
  const int t16 = blockIdx.x * 4 + w;
  const int lr = l >> 4, lc = l & 15;
  int nld = 0; float dld = 0.f;
  if (l < 16) {
    nld = nodes[row0 + t16 * 16 + l];
    dld = mail_time[nld] - mem_time[nld];
  }
  const int   nrow = __shfl(nld, lc);
  const float drow = __shfl(dld, lc);
  const float* mailp = mail_data + (size_t)nrow * 384 + lr * 8;
  const float* memp  = mem_data  + (size_t)nrow * 128 + lr * 8;
  unsigned short* dst = Abuf + (size_t)t16 * (20 * 512) + l * 8;

  #pragma unroll
  for (int kt = 0; kt < 12; ++kt) {
    const float4 v0 = ((const float4*)(mailp + kt * 32))[0];
    const float4 v1 = ((const float4*)(mailp + kt * 32))[1];
    *(bf16x8*)(dst + kt * 512) = pack8(v0, v1);
  }
  #pragma unroll
  for (int kt = 12; kt < 16; ++kt) {
    const int c0 = kt * 32 + lr * 8 - 384;
    const float4 w0 = ((const float4*)(time_w + c0))[0];
    const float4 w1 = ((const float4*)(time_w + c0))[1];
    const float4 b0 = ((const float4*)(time_b + c0))[0];
    const float4 b1 = ((const float4*)(time_b + c0))[1];
    float4 u, v;
    u.x = cosf(fmaf(drow, w0.x, b0.x)); u.y = cosf(fmaf(drow, w0.y, b0.y));
    u.z = cosf(fmaf(drow, w0.z, b0.z)); u.w = cosf(fmaf(drow, w0.w, b0.w));
    v.x = cosf(fmaf(drow, w1.x, b1.x)); v.y = cosf(fmaf(drow, w1.y, b1.y));
    v.z = cosf(fmaf(drow, w1.z, b1.z)); v.w = cosf(fmaf(drow, w1.w, b1.w));
    *(bf16x8*)(dst + kt * 512) = pack8(u, v);
  }
  #pragma unroll
  for (int kt = 16; kt < 20; ++kt) {
    const float4 v0 = ((const float4*)(memp + (kt - 16) * 32))[0];
    const float4 v1 = ((const float4*)(memp + (kt - 16) * 32))[1];
    *(bf16x8*)(dst + kt * 512) = pack8(v0, v1);
  }
}

// ---------------- k1_gemm: barrier-free MFMA GEMM + GRU epilogue ----------------
DEVFN void ldk1(const unsigned short* Ap0, const unsigned short* Ap1,
                const unsigned short* Bp, int kt, bf16x8 (&A)[2], bf16x8 (&B)[8]) {
  A[0] = *(const bf16x8*)(Ap0 + (size_t)kt * 512);
  A[1] = *(const bf16x8*)(Ap1 + (size_t)kt * 512);
  #pragma unroll
  for (int bn = 0; bn < 8; ++bn)
    B[bn] = *(const bf16x8*)(Bp + ((size_t)kt * 32 + bn) * 512);
}
DEVFN void mmk1(f32x4 (&acc)[2][8], const bf16x8 (&A)[2], const bf16x8 (&B)[8]) {
  #pragma unroll
  for (int bn = 0; bn < 8; ++bn) {
    acc[0][bn] = MFMA16(A[0], B[bn], acc[0][bn]);
    acc[1][bn] = MFMA16(A[1], B[bn], acc[1][bn]);
  }
}

__global__ __launch_bounds__(512) void k1_gemm(
    const unsigned short* __restrict__ Abuf, const unsigned short* __restrict__ WcatP,
    const float* __restrict__ bcat, const int* __restrict__ nodes,
    const float* __restrict__ nfeat, unsigned short* __restrict__ hb, int row0)
{
  const int w = threadIdx.x >> 6, l = threadIdx.x & 63;
  const int wm = w >> 2, wn = w & 3;
  const int lr = l >> 4, lc = l & 15;
  const int t16base = blockIdx.x * 4 + wm * 2;
  const unsigned short* Ap0 = Abuf + (size_t)t16base * (20 * 512) + l * 8;
  const unsigned short* Ap1 = Ap0 + 20 * 512;
  const unsigned short* Bp  = WcatP + (size_t)(wn * 8) * 512 + l * 8;

  f32x4 acc[2][8];
  #pragma unroll
  for (int m = 0; m < 2; ++m)
    #pragma unroll
    for (int bn = 0; bn < 8; ++bn) acc[m][bn] = (f32x4){0.f, 0.f, 0.f, 0.f};

  bf16x8 A0[2], A1[2], B0[8], B1[8];
  ldk1(Ap0, Ap1, Bp, 0, A0, B0);
  for (int kt = 0; kt < 20; kt += 2) {
    ldk1(Ap0, Ap1, Bp, kt + 1, A1, B1);
    mmk1(acc, A0, B0);
    if (kt + 2 < 20) ldk1(Ap0, Ap1, Bp, kt + 2, A0, B0);
    mmk1(acc, A1, B1);
  }

  float bg[4][2];
  #pragma unroll
  for (int g = 0; g < 4; ++g)
    #pragma unroll
    for (int jb = 0; jb < 2; ++jb) bg[g][jb] = bcat[wn * 128 + (g * 2 + jb) * 16 + lc];

  #pragma unroll
  for (int mt = 0; mt < 2; ++mt) {
    const int t16 = t16base + mt;
    #pragma unroll
    for (int rr = 0; rr < 4; ++rr) {
      const int rloc16 = lr * 4 + rr;
      const int grow   = row0 + t16 * 16 + rloc16;
      const int n      = nodes[grow];
      #pragma unroll
      for (int jb = 0; jb < 2; ++jb) {
        const int j = wn * 32 + jb * 16 + lc;
        const float aR  = acc[mt][0 + jb][rr] + bg[0][jb];
        const float aZ  = acc[mt][2 + jb][rr] + bg[1][jb];
        const float aNi = acc[mt][4 + jb][rr] + bg[2][jb];
        const float aNh = acc[mt][6 + jb][rr] + bg[3][jb];
        const float r_  = sigmoidf_(aR);
        const float z_  = sigmoidf_(aZ);
        const float n_  = tanhf(aNi + r_ * aNh);
        const int ke = jb * 16 + lc;
        const float mem = bf2f(Abuf[((size_t)t16 * 20 + 16 + wn) * 512 +
                                    ((ke >> 3) * 16 + rloc16) * 8 + (ke & 7)]);
        const float h = nfeat[(size_t)n * 128 + j] + (1.0f - z_) * n_ + z_ * mem;
        hb[(size_t)grow * 128 + j] = f2bf(h);
      }
    }
  }
}

// ---------------- kB: build KVin (chunk) fragment-major bf16 ----------------
__global__ __launch_bounds__(256) void kB_build(
    const unsigned short* __restrict__ hb, const int* __restrict__ eids,
    const float* __restrict__ dt_nbr, const float* __restrict__ efeat,
    const float* __restrict__ time_w, const float* __restrict__ time_b,
    unsigned short* __restrict__ KVin, int row0)
{
  const int w = threadIdx.x >> 6, l = threadIdx.x & 63;
  const int t16 = blockIdx.x * 4 + w;
  const int lr = l >> 4, lc = l & 15;
  int eld = 0; float dld = 0.f;
  if (l < 16) {
    eld = eids[row0 + t16 * 16 + l];
    dld = dt_nbr[row0 + t16 * 16 + l];
  }
  const int   eid = __shfl(eld, lc);
  const float dt  = __shfl(dld, lc);
  const unsigned short* hbp = hb + (size_t)(ND_ + row0 + t16 * 16 + lc) * 128 + lr * 8;
  const float* efp = efeat + (size_t)eid * 128 + lr * 8;
  unsigned short* dst = KVin + (size_t)t16 * (12 * 512) + l * 8;

  #pragma unroll
  for (int kt = 0; kt < 4; ++kt)
    *(bf16x8*)(dst + kt * 512) = *(const bf16x8*)(hbp + kt * 32);
  #pragma unroll
  for (int kt = 4; kt < 8; ++kt) {
    const float4 v0 = ((const float4*)(efp + (kt - 4) * 32))[0];
    const float4 v1 = ((const float4*)(efp + (kt - 4) * 32))[1];
    *(bf16x8*)(dst + kt * 512) = pack8(v0, v1);
  }
  #pragma unroll
  for (int kt = 8; kt < 12; ++kt) {
    const int c0 = kt * 32 + lr * 8 - 256;
    const float4 w0 = ((const float4*)(time_w + c0))[0];
    const float4 w1 = ((const float4*)(time_w + c0))[1];
    const float4 b0 = ((const float4*)(time_b + c0))[0];
    const float4 b1 = ((const float4*)(time_b + c0))[1];
    float4 u, v;
    u.x = cosf(fmaf(dt, w0.x, b0.x)); u.y = cosf(fmaf(dt, w0.y, b0.y));
    u.z = cosf(fmaf(dt, w0.z, b0.z)); u.w = cosf(fmaf(dt, w0.w, b0.w));
    v.x = cosf(fmaf(dt, w1.x, b1.x)); v.y = cosf(fmaf(dt, w1.y, b1.y));
    v.z = cosf(fmaf(dt, w1.z, b1.z)); v.w = cosf(fmaf(dt, w1.w, b1.w));
    *(bf16x8*)(dst + kt * 512) = pack8(u, v);
  }
}

// ---------------- k2_gemm: KV projection GEMM -> KVb ----------------
DEVFN void ldk2(const unsigned short* Ap0, const unsigned short* Ap1,
                const unsigned short* Bp, int kt, bf16x8 (&A)[2], bf16x8 (&B)[4]) {
  A[0] = *(const bf16x8*)(Ap0 + (size_t)kt * 512);
  A[1] = *(const bf16x8*)(Ap1 + (size_t)kt * 512);
  #pragma unroll
  for (int bn = 0; bn < 4; ++bn)
    B[bn] = *(const bf16x8*)(Bp + ((size_t)kt * 16 + bn) * 512);
}
DEVFN void mmk2(f32x4 (&acc)[2][4], const bf16x8 (&A)[2], const bf16x8 (&B)[4]) {
  #pragma unroll
  for (int bn = 0; bn < 4; ++bn) {
    acc[0][bn] = MFMA16(A[0], B[bn], acc[0][bn]);
    acc[1][bn] = MFMA16(A[1], B[bn], acc[1][bn]);
  }
}

__global__ __launch_bounds__(512) void k2_gemm(
    const unsigned short* __restrict__ KVin, const unsigned short* __restrict__ WkvP,
    const float* __restrict__ bkv, unsigned short* __restrict__ KVb, int row0)
{
  const int w = threadIdx.x >> 6, l = threadIdx.x & 63;
  const int wm = w >> 2, wn = w & 3;
  const int lr = l >> 4, lc = l & 15;
  const int t16base = blockIdx.x * 4 + wm * 2;
  const unsigned short* Ap0 = KVin + (size_t)t16base * (12 * 512) + l * 8;
  const unsigned short* Ap1 = Ap0 + 12 * 512;
  const unsigned short* Bp  = WkvP + (size_t)(wn * 4) * 512 + l * 8;

  f32x4 acc[2][4];
  #pragma unroll
  for (int m = 0; m < 2; ++m)
    #pragma unroll
    for (int bn = 0; bn < 4; ++bn) acc[m][bn] = (f32x4){0.f, 0.f, 0.f, 0.f};

  bf16x8 A0[2], A1[2], B0[4], B1[4];
  ldk2(Ap0, Ap1, Bp, 0, A0, B0);
  for (int kt = 0; kt < 12; kt += 2) {
    ldk2(Ap0, Ap1, Bp, kt + 1, A1, B1);
    mmk2(acc, A0, B0);
    if (kt + 2 < 12) ldk2(Ap0, Ap1, Bp, kt + 2, A0, B0);
    mmk2(acc, A1, B1);
  }

  float bb[4];
  #pragma unroll
  for (int bn = 0; bn < 4; ++bn) bb[bn] = bkv[wn * 64 + bn * 16 + lc];

  #pragma unroll
  for (int mt = 0; mt < 2; ++mt) {
    const int t16 = t16base + mt;
    #pragma unroll
    for (int rr = 0; rr < 4; ++rr) {
      const size_t grow = (size_t)(row0 + t16 * 16 + lr * 4 + rr);
      #pragma unroll
      for (int bn = 0; bn < 4; ++bn)
        KVb[grow * 256 + wn * 64 + bn * 16 + lc] = f2bf(acc[mt][bn][rr] + bb[bn]);
    }
  }
}

// ---------------- kQ_gemm: Q = dst_h @ wq[:, :128]^T + qzero -> Qb (bf16) ----------------
// A fragments read on-the-fly from hb (per-lane 16B loads); B = WqB fragment-major.
__global__ __launch_bounds__(512) void kQ_gemm(
    const unsigned short* __restrict__ hb, const unsigned short* __restrict__ WqB,
    const float* __restrict__ qzero, unsigned short* __restrict__ Qb)
{
  const int w = threadIdx.x >> 6, l = threadIdx.x & 63;
  const int wm = w >> 2, wn = w & 3;
  const int lr = l >> 4, lc = l & 15;
  const int t16base = blockIdx.x * 4 + wm * 2;
  const unsigned short* Ar0 = hb + (size_t)(t16base * 16 + lc) * 128 + lr * 8;
  const unsigned short* Ar1 = Ar0 + 16 * 128;

  f32x4 acc[2][2];
  #pragma unroll
  for (int m = 0; m < 2; ++m)
    #pragma unroll
    for (int bn = 0; bn < 2; ++bn) acc[m][bn] = (f32x4){0.f, 0.f, 0.f, 0.f};

  #pragma unroll
  for (int kt = 0; kt < 4; ++kt) {
    const bf16x8 a0 = *(const bf16x8*)(Ar0 + kt * 32);
    const bf16x8 a1 = *(const bf16x8*)(Ar1 + kt * 32);
    #pragma unroll
    for (int bn = 0; bn < 2; ++bn) {
      const bf16x8 b = *(const bf16x8*)(WqB + ((size_t)(kt * 8 + wn * 2 + bn) * 64 + l) * 8);
      acc[0][bn] = MFMA16(a0, b, acc[0][bn]);
      acc[1][bn] = MFMA16(a1, b, acc[1][bn]);
    }
  }

  #pragma unroll
  for (int mt = 0; mt < 2; ++mt)
    #pragma unroll
    for (int rr = 0; rr < 4; ++rr) {
      const int row = (t16base + mt) * 16 + lr * 4 + rr;
      #pragma unroll
      for (int bn = 0; bn < 2; ++bn) {
        const int col = (wn * 2 + bn) * 16 + lc;
        Qb[(size_t)row * 128 + col] = f2bf(acc[mt][bn][rr] + qzero[col]);
      }
    }
}

// ---------------- kAtt: per-row 2-head attention over 10 neighbors -> aggb (bf16) ----------------
// 256 threads = 4 waves; each wave owns one dst row. Lane l covers dims l (head0) and 64+l (head1).
__global__ __launch_bounds__(256) void kAtt(
    const unsigned short* __restrict__ Qb, const unsigned short* __restrict__ KVb,
    unsigned short* __restrict__ aggb)
{
  const int w = threadIdx.x >> 6, l = threadIdx.x & 63;
  const int i = blockIdx.x * 4 + w;
  const float q0 = bf2f(Qb[(size_t)i * 128 + l]);
  const float q1 = bf2f(Qb[(size_t)i * 128 + 64 + l]);
  const unsigned short* base = KVb + (size_t)i * K_ * 256;

  float s0[K_], s1[K_], v0[K_], v1[K_];
  #pragma unroll
  for (int kk = 0; kk < K_; ++kk) {
    const unsigned short* rp = base + kk * 256;
    const float k0 = bf2f(rp[l]);
    const float k1 = bf2f(rp[64 + l]);
    v0[kk] = bf2f(rp[128 + l]);
    v1[kk] = bf2f(rp[192 + l]);
    float p0 = q0 * k0, p1 = q1 * k1;
    #pragma unroll
    for (int t = 32; t; t >>= 1) { p0 += __shfl_xor(p0, t); p1 += __shfl_xor(p1, t); }
    s0[kk] = p0; s1[kk] = p1;
  }
  float m0 = s0[0], m1 = s1[0];
  #pragma unroll
  for (int kk = 1; kk < K_; ++kk) { m0 = fmaxf(m0, s0[kk]); m1 = fmaxf(m1, s1[kk]); }
  float sum0 = 0.f, sum1 = 0.f, a0 = 0.f, a1 = 0.f;
  #pragma unroll
  for (int kk = 0; kk < K_; ++kk) {
    const float e0 = expf(s0[kk] - m0);
    const float e1 = expf(s1[kk] - m1);
    sum0 += e0; sum1 += e1;
    a0 += e0 * v0[kk]; a1 += e1 * v1[kk];
  }
  aggb[(size_t)i * 128 + l]      = f2bf(a0 / sum0);
  aggb[(size_t)i * 128 + 64 + l] = f2bf(a1 / sum1);
}

// ---------------- kO_gemm: out = relu([dst_h|agg] @ wo^T + bo) -> OutR (fp32) ----------------
__global__ __launch_bounds__(512) void kO_gemm(
    const unsigned short* __restrict__ hb, const unsigned short* __restrict__ aggb,
    const unsigned short* __restrict__ WoB, const float* __restrict__ bo,
    float* __restrict__ OutR)
{
  const int w = threadIdx.x >> 6, l = threadIdx.x & 63;
  const int wm = w >> 2, wn = w & 3;
  const int lr = l >> 4, lc = l & 15;
  const int t16base = blockIdx.x * 4 + wm * 2;
  const unsigned short* Ah0 = hb   + (size_t)(t16base * 16 + lc) * 128 + lr * 8;
  const unsigned short* Ah1 = Ah0 + 16 * 128;
  const unsigned short* Ag0 = aggb + (size_t)(t16base * 16 + lc) * 128 + lr * 8;
  const unsigned short* Ag1 = Ag0 + 16 * 128;

  f32x4 acc[2][2];
  #pragma unroll
  for (int m = 0; m < 2; ++m)
    #pragma unroll
    for (int bn = 0; bn < 2; ++bn) acc[m][bn] = (f32x4){0.f, 0.f, 0.f, 0.f};

  #pragma unroll
  for (int kt = 0; kt < 8; ++kt) {
    const bf16x8 a0 = (kt < 4) ? *(const bf16x8*)(Ah0 + kt * 32)
                               : *(const bf16x8*)(Ag0 + (kt - 4) * 32);
    const bf16x8 a1 = (kt < 4) ? *(const bf16x8*)(Ah1 + kt * 32)
                               : *(const bf16x8*)(Ag1 + (kt - 4) * 32);
    #pragma unroll
    for (int bn = 0; bn < 2; ++bn) {
      const bf16x8 b = *(const bf16x8*)(WoB + ((size_t)(kt * 8 + wn * 2 + bn) * 64 + l) * 8);
      acc[0][bn] = MFMA16(a0, b, acc[0][bn]);
      acc[1][bn] = MFMA16(a1, b, acc[1][bn]);
    }
  }

  #pragma unroll
  for (int mt = 0; mt < 2; ++mt)
    #pragma unroll
    for (int rr = 0; rr < 4; ++rr) {
      const int row = (t16base + mt) * 16 + lr * 4 + rr;
      #pragma unroll
      for (int bn = 0; bn < 2; ++bn) {
        const int col = (wn * 2 + bn) * 16 + lc;
        OutR[(size_t)row * 128 + col] = fmaxf(acc[mt][bn][rr] + bo[col], 0.f);
      }
    }
}

// ---------------- kLN: LayerNorm -> emb (fp32) ----------------
__global__ __launch_bounds__(256) void kLN(
    const float* __restrict__ OutR, const float* __restrict__ ln_g,
    const float* __restrict__ ln_b, float* __restrict__ emb)
{
  __shared__ float ps[4], pq[4];
  const int tid = threadIdx.x;
  const int r = tid >> 7, c = tid & 127, wv = tid >> 6;
  const int row = blockIdx.x * 2 + r;
  const float x = OutR[(size_t)row * 128 + c];
  float s = x, q = x * x;
  #pragma unroll
  for (int t = 32; t; t >>= 1) { s += __shfl_xor(s, t); q += __shfl_xor(q, t); }
  if ((tid & 63) == 0) { ps[wv] = s; pq[wv] = q; }
  __syncthreads();
  const float sum = ps[r * 2] + ps[r * 2 + 1];
  const float sq  = pq[r * 2] + pq[r * 2 + 1];
  const float mu  = sum * (1.0f / 128.0f);
  const float var = sq * (1.0f / 128.0f) - mu * mu;
  emb[(size_t)row * 128 + c] = ln_g[c] * (x - mu) * rsqrtf(var + 1e-5f) + ln_b[c];
}

// ---------------- k3: edge predictor -> out[B][2] ----------------
__global__ __launch_bounds__(128) void k3_ep(
    const float* __restrict__ emb, const float4* __restrict__ SwP,
    const float4* __restrict__ DwP, const float* __restrict__ ep_sb,
    const float* __restrict__ ep_db, const float* __restrict__ ep_ow,
    const float* __restrict__ ep_ob, float* __restrict__ out)
{
  __shared__ float se[128], de[128], ne[128];
  __shared__ float redp[2], redn[2];
  const int c = threadIdx.x;
  const int i = blockIdx.x;
  se[c] = emb[(size_t)i * 128 + c];
  de[c] = emb[(size_t)(B_ + i) * 128 + c];
  ne[c] = emb[(size_t)(2 * B_ + i) * 128 + c];
  __syncthreads();
  float sacc = ep_sb[c], dacc = ep_db[c], nacc = ep_db[c];
  for (int k4 = 0; k4 < 32; ++k4) {
    const float4 sw = SwP[k4 * 128 + c];
    const float4 dw = DwP[k4 * 128 + c];
    sacc = dot4(((const float4*)se)[k4], sw, sacc);
    dacc = dot4(((const float4*)de)[k4], dw, dacc);
    nacc = dot4(((const float4*)ne)[k4], dw, nacc);
  }
  const float ow = ep_ow[c];
  float pp = fmaxf(sacc + dacc, 0.f) * ow;
  float pn = fmaxf(sacc + nacc, 0.f) * ow;
  for (int t = 32; t; t >>= 1) { pp += __shfl_xor(pp, t); pn += __shfl_xor(pn, t); }
  if ((c & 63) == 0) { redp[c >> 6] = pp; redn[c >> 6] = pn; }
  __syncthreads();
  if (c == 0) {
    const float ob = ep_ob[0];
    out[i * 2]     = redp[0] + redp[1] + ob;
    out[i * 2 + 1] = redn[0] + redn[1] + ob;
  }
}

// ---------------- launch ----------------
extern "C" void kernel_launch(void* const* d_in, const int* in_sizes, int n_in,
                              void* d_out, int out_size, void* d_ws, size_t ws_size,
                              hipStream_t stream) {
  const int*   nodes     = (const int*)d_in[0];
  const int*   eids      = (const int*)d_in[1];
  const float* dt_nbr    = (const float*)d_in[2];
  const float* nfeat     = (const float*)d_in[3];
  const float* mem_data  = (const float*)d_in[4];
  const float* mem_time  = (const float*)d_in[5];
  const float* mail_data = (const float*)d_in[6];
  const float* mail_time = (const float*)d_in[7];
  const float* efeat     = (const float*)d_in[8];
  const float* time_w    = (const float*)d_in[9];
  const float* time_b    = (const float*)d_in[10];
  const float* gru_w_ih  = (const float*)d_in[11];
  const float* gru_w_hh  = (const float*)d_in[12];
  const float* gru_b_ih  = (const float*)d_in[13];
  const float* gru_b_hh  = (const float*)d_in[14];
  const float* wq        = (const float*)d_in[15];
  const float* bq        = (const float*)d_in[16];
  const float* wk        = (const float*)d_in[17];
  const float* bk        = (const float*)d_in[18];
  const float* wv        = (const float*)d_in[19];
  const float* bv        = (const float*)d_in[20];
  const float* wo        = (const float*)d_in[21];
  const float* bo        = (const float*)d_in[22];
  const float* ln_g      = (const float*)d_in[23];
  const float* ln_b      = (const float*)d_in[24];
  const float* ep_sw     = (const float*)d_in[25];
  const float* ep_sb     = (const float*)d_in[26];
  const float* ep_dw     = (const float*)d_in[27];
  const float* ep_db     = (const float*)d_in[28];
  const float* ep_ow     = (const float*)d_in[29];
  const float* ep_ob     = (const float*)d_in[30];
  float* out = (float*)d_out;
  float* ws  = (float*)d_ws;

  unsigned short* OVL   = (unsigned short*)(ws + OFF_OVL);   // Abuf / KVin chunks
  unsigned short* Qb    = (unsigned short*)(ws + OFF_QB);
  unsigned short* aggb  = (unsigned short*)(ws + OFF_AGG);
  float*          OutR  = ws + OFF_OUTR;
  unsigned short* hb    = (unsigned short*)(ws + OFF_HB);
  unsigned short* KVb   = (unsigned short*)(ws + OFF_KVB);
  float*          emb   = ws + OFF_EMB;
  unsigned short* WcatP = (unsigned short*)(ws + OFF_WCAT);
  unsigned short* WkvP  = (unsigned short*)(ws + OFF_WKV);
  float*          bcat  = ws + OFF_BCAT;
  float*          bkv   = ws + OFF_BKV;
  unsigned short* WqB   = (unsigned short*)(ws + OFF_WQB);
  unsigned short* WoB   = (unsigned short*)(ws + OFF_WOB);
  float4*         SwP   = (float4*)(ws + OFF_SWP);
  float4*         DwP   = (float4*)(ws + OFF_DWP);
  float*          qzero = ws + OFF_QZ;

  k0_packWcat<<<1280, 256, 0, stream>>>(gru_w_ih, gru_w_hh, WcatP);
  k0_packWkv<<<384, 256, 0, stream>>>(wk, wv, WkvP);
  k0_packQO<<<192, 256, 0, stream>>>(wq, wo, WqB, WoB);
  k0_misc<<<35, 256, 0, stream>>>(ep_sw, ep_dw, gru_b_ih, gru_b_hh, bk, bv,
                                  SwP, DwP, bcat, bkv);
  k0_qzero<<<1, 128, 0, stream>>>(time_b, wq, bq, qzero);

  for (int c = 0; c < 4; ++c) {
    kA_build<<<CH1 / 64, 256, 0, stream>>>(nodes, mail_data, mem_data, mail_time,
                                           mem_time, time_w, time_b, OVL, c * CH1);
    k1_gemm<<<CH1 / 64, 512, 0, stream>>>(OVL, WcatP, bcat, nodes, nfeat, hb, c * CH1);
  }
  for (int c = 0; c < 4; ++c) {
    kB_build<<<CH2 / 64, 256, 0, stream>>>(hb, eids, dt_nbr, efeat, time_w, time_b,
                                           OVL, c * CH2);
    k2_gemm<<<CH2 / 64, 512, 0, stream>>>(OVL, WkvP, bkv, KVb, c * CH2);
  }
  kQ_gemm<<<ND_ / 64, 512, 0, stream>>>(hb, WqB, qzero, Qb);
  kAtt<<<ND_ / 4, 256, 0, stream>>>(Qb, KVb, aggb);
  kO_gemm<<<ND_ / 64, 512, 0, stream>>>(hb, aggb, WoB, bo, OutR);
  kLN<<<ND_ / 2, 256, 0, stream>>>(OutR, ln_g, ln_b, emb);
  k3_ep<<<B_, 128, 0, stream>>>(emb, SwP, DwP, ep_sb, ep_db, ep_ow, ep_ob, out);
}